// Round 11
// baseline (147.258 us; speedup 1.0000x reference)
//
#include <hip/hip_runtime.h>
#include <math.h>

#define E_DIM 768
#define S_LEN 1024
#define B_SZ 2
#define H_CNT 12
#define D_HEAD 64
#define M_DIM 768
#define Q_STRIDE 4
#define N_FC1 771            // only M+Q-1 columns of fc1 are consumed

typedef __attribute__((ext_vector_type(8))) short bf16x8;
typedef __attribute__((ext_vector_type(4))) float f32x4;

#define AS1 __attribute__((address_space(1)))
#define AS3 __attribute__((address_space(3)))

__device__ __forceinline__ void gld_lds16(void* lds, const void* g) {
    __builtin_amdgcn_global_load_lds((const AS1 void*)g, (AS3 void*)lds, 16, 0, 0);
}

__device__ __forceinline__ short f2bf(float f) {
    unsigned u = __float_as_uint(f);
    unsigned r = (u + 0x7fffu + ((u >> 16) & 1u)) >> 16;
    return (short)r;
}

__device__ __forceinline__ float bf2f(short s) {
    return __uint_as_float(((unsigned)(unsigned short)s) << 16);
}

// pack two f32 -> one dword of 2 bf16 (RNE), single instruction
__device__ __forceinline__ unsigned cvt_pk_bf16(float lo, float hi) {
    unsigned r;
    asm("v_cvt_pk_bf16_f32 %0, %1, %2" : "=v"(r) : "v"(lo), "v"(hi));
    return r;
}

// ---------------- block reduction helper (256 threads, 4 waves) ------------

__device__ __forceinline__ float block_reduce_sum(float v, volatile float* red) {
#pragma unroll
    for (int off = 32; off > 0; off >>= 1) v += __shfl_xor(v, off);
    __syncthreads();
    if ((threadIdx.x & 63) == 0) red[threadIdx.x >> 6] = v;
    __syncthreads();
    return red[0] + red[1] + red[2] + red[3];
}

// ------------- preamble: ln1 + bias concat + QKV weight conversion --------
// R20: preamble converts ONLY the QKV weights; Wo/fc1/vqc/fc2 conversion is
// backfilled into the QKV GEMM dispatch (see gemm_bf16 OUTMODE==3).

__global__ __launch_bounds__(256) void preamble(
        const float* __restrict__ Wq, const float* __restrict__ Wk,
        const float* __restrict__ Wv, const float* __restrict__ Wo,
        const float* __restrict__ fc1W, const float* __restrict__ vqcW,
        const float* __restrict__ fc2W, short* __restrict__ dst,
        const float* __restrict__ bq, const float* __restrict__ bk,
        const float* __restrict__ bv, float* __restrict__ bqkv,
        const float* __restrict__ x, const float* __restrict__ ln1_w,
        const float* __restrict__ ln1_b, short* __restrict__ actb) {
    __shared__ float red[4];
    int tid = threadIdx.x;
    if (blockIdx.x < 2048) {          // ln1
        int row = blockIdx.x;
        const float* xr = x + (size_t)row * E_DIM;
        float v0 = xr[tid], v1 = xr[tid + 256], v2 = xr[tid + 512];
        float s = block_reduce_sum(v0 + v1 + v2, red);
        float mu = s * (1.0f / E_DIM);
        float d0 = v0 - mu, d1 = v1 - mu, d2 = v2 - mu;
        float var = block_reduce_sum(d0 * d0 + d1 * d1 + d2 * d2, red) * (1.0f / E_DIM);
        float rs = rsqrtf(var + 1e-5f);
        short* orow = actb + (size_t)row * E_DIM;
        orow[tid]       = f2bf(d0 * rs * ln1_w[tid]       + ln1_b[tid]);
        orow[tid + 256] = f2bf(d1 * rs * ln1_w[tid + 256] + ln1_b[tid + 256]);
        orow[tid + 512] = f2bf(d2 * rs * ln1_w[tid + 512] + ln1_b[tid + 512]);
        return;
    }
    if (blockIdx.x == 2048) {         // bias concat
#pragma unroll
        for (int u = 0; u < 9; u++) {
            int i = tid + u * 256;
            float v = (i < 768) ? bq[i] : (i < 1536) ? bk[i - 768] : bv[i - 1536];
            bqkv[i] = v;
        }
        return;
    }
    int t = (blockIdx.x - 2049) * 256 + tid;      // float4 index
    if (t >= 442368) return;                      // QKV weights only: 1769472 / 4
    int e = t * 4;
    const float* src; int off;
    if      (e < 589824)  { src = Wq;   off = e; }
    else if (e < 1179648) { src = Wk;   off = e - 589824; }
    else                  { src = Wv;   off = e - 1179648; }
    float4 v = *(const float4*)(src + off);
    short4 o = make_short4(f2bf(v.x), f2bf(v.y), f2bf(v.z), f2bf(v.w));
    *(short4*)(dst + e) = o;
}

// ---------------- bf16 MFMA NT GEMM (BK=64, double-buffered, MR-templated) -
// MR x 128 tile, BK=64 (two MRx32 sub-slabs), double-buffered (one barrier
// per iteration). LDS 48 KB at MR=64 -> 3 blocks/CU, matching 768-block
// balanced grids (R10). R18/R7 lesson: MR=128 shrinks grids to 288-384
// blocks = 1.1-1.5/CU -> grid imbalance costs more than the tile wins.
// OUTMODE: 2 = bias+GELU+bf16 transpose-scatter (vqc); 3 = QKV split
//          (+ fp32 q/k row-norm side outputs qnG/knG; + R20 appended
//          weight-converter blocks at blockIdx.y >= 32); 5 = bf16 partial.

template <int OUTMODE, int MR>
__global__ __launch_bounds__(256, 2) void gemm_bf16(
        const short* __restrict__ A, int lda,
        const short* __restrict__ W, int ldw,
        const float* __restrict__ bias,
        void* __restrict__ outp, int ldo, size_t spitch,
        short* __restrict__ Kfp, short* __restrict__ Vfp,
        int N, int klen, int dogelu,
        float* __restrict__ qnG, float* __restrict__ knG,
        const float* __restrict__ cW0, const float* __restrict__ cW1,
        const float* __restrict__ cW2, const float* __restrict__ cW3,
        short* __restrict__ cdst) {
    if constexpr (OUTMODE == 3) {
        // appended weight-converter blocks (dispatched last: y >= 32)
        if (blockIdx.y >= 32) {
            int cid = (blockIdx.y - 32) * 18 + blockIdx.x;
            int tid = threadIdx.x;
#pragma unroll
            for (int u = 0; u < 4; u++) {
                int t = cid * 1024 + u * 256 + tid;   // float4 idx in remaining region
                if (t < 1032768) {
                    int e = 1769472 + t * 4;          // global float idx
                    const float* src; int off;
                    if      (e < 2359296) { src = cW0; off = e - 1769472; }  // Wo
                    else if (e < 2951424) { src = cW1; off = e - 2359296; }  // fc1
                    else if (e < 3541248) { src = cW2; off = e - 2951424; }  // vqc
                    else                  { src = cW3; off = e - 3541248; }  // fc2
                    float4 v = *(const float4*)(src + off);
                    short4 o = make_short4(f2bf(v.x), f2bf(v.y), f2bf(v.z), f2bf(v.w));
                    *(short4*)(cdst + e) = o;
                }
            }
            return;
        }
    }
    constexpr int MI = MR / 32;
    constexpr int AH = MR * 32;
    constexpr int NA = MR / 64;
    constexpr int ASL = 2 * AH;
    __shared__ short At[2 * ASL];
    __shared__ short Bt[2 * 8192];
    const int tid = threadIdx.x;
    const int lane = tid & 63;
    const int wave = tid >> 6;
    const int wr = (wave >> 1) * (MI * 16);
    const int wc = (wave & 1) * 64;
    const int ml = lane & 15;
    const int kq = lane >> 4;
    const int row0 = blockIdx.y * MR;
    const int col0 = blockIdx.x * 128;
    const int kbase = blockIdx.z * klen;

    const short* Ag[NA]; int aoff[NA];
#pragma unroll
    for (int u = 0; u < NA; u++) {
        int c = tid + u * 256;
        int am = c >> 2, ak = ((c & 3) ^ ((am >> 1) & 3)) * 8;
        Ag[u] = A + (size_t)(row0 + am) * lda + ak + kbase;
        aoff[u] = c * 8;
    }
    const int c0 = tid, c1 = tid + 256;
    const int bm0 = c0 >> 2, bk0 = (((c0 & 3) ^ ((bm0 >> 1) & 3))) * 8;
    const int bm1 = c1 >> 2, bk1 = (((c1 & 3) ^ ((bm1 >> 1) & 3))) * 8;
    int wrow0 = col0 + bm0; if (wrow0 > N - 1) wrow0 = N - 1;
    int wrow1 = col0 + bm1; if (wrow1 > N - 1) wrow1 = N - 1;
    const short* Wg0 = W + (size_t)wrow0 * ldw + bk0 + kbase;
    const short* Wg1 = W + (size_t)wrow1 * ldw + bk1 + kbase;

    const int kxor = (kq ^ ((ml >> 1) & 3)) * 8;

    f32x4 acc[MI][4];
#pragma unroll
    for (int i = 0; i < MI; i++)
#pragma unroll
        for (int j = 0; j < 4; j++) acc[i][j] = {0.f, 0.f, 0.f, 0.f};

    auto stage = [&](int buf, int k0) {
        short* Ab = At + buf * ASL;
        short* Bb = Bt + buf * 8192;
#pragma unroll
        for (int u = 0; u < NA; u++) {
            gld_lds16(Ab + aoff[u], Ag[u] + k0);
            gld_lds16(Ab + AH + aoff[u], Ag[u] + k0 + 32);
        }
        gld_lds16(Bb + c0 * 8, Wg0 + k0);
        gld_lds16(Bb + c1 * 8, Wg1 + k0);
        gld_lds16(Bb + 4096 + c0 * 8, Wg0 + k0 + 32);
        gld_lds16(Bb + 4096 + c1 * 8, Wg1 + k0 + 32);
    };

    stage(0, 0);
    int cur = 0;
    for (int k0 = 0; k0 < klen; k0 += 64) {
        __syncthreads();
        if (k0 + 64 < klen) stage(cur ^ 1, k0 + 64);
        const short* Ac = At + cur * ASL;
        const short* Bc = Bt + cur * 8192;
#pragma unroll
        for (int half = 0; half < 2; half++) {
            const short* Ah = Ac + half * AH;
            const short* Bh = Bc + half * 4096;
            bf16x8 af[MI], bfr[4];
#pragma unroll
            for (int i = 0; i < MI; i++)
                af[i] = *(const bf16x8*)&Ah[(wr + i * 16 + ml) * 32 + kxor];
#pragma unroll
            for (int j = 0; j < 4; j++)
                bfr[j] = *(const bf16x8*)&Bh[(wc + j * 16 + ml) * 32 + kxor];
#pragma unroll
            for (int i = 0; i < MI; i++)
#pragma unroll
                for (int j = 0; j < 4; j++)
                    acc[i][j] = __builtin_amdgcn_mfma_f32_16x16x32_bf16(af[i], bfr[j], acc[i][j], 0, 0, 0);
        }
        cur ^= 1;
    }

    // epilogue: C/D layout col = lane&15, row = (lane>>4)*4 + reg
    float sq[MI][4];
    if constexpr (OUTMODE == 3) {
#pragma unroll
        for (int i = 0; i < MI; i++)
#pragma unroll
            for (int rr = 0; rr < 4; rr++) sq[i][rr] = 0.f;
    }
#pragma unroll
    for (int i = 0; i < MI; i++) {
#pragma unroll
        for (int j = 0; j < 4; j++) {
#pragma unroll
            for (int rr = 0; rr < 4; rr++) {
                int r = row0 + wr + i * 16 + kq * 4 + rr;
                int c = col0 + wc + j * 16 + ml;
                if (c < N) {
                    float v = acc[i][j][rr];
                    if (OUTMODE < 4) v += bias[c];
                    if (OUTMODE == 2 && dogelu)
                        v = 0.5f * v * (1.0f + erff(v * 0.70710678118654752f));
                    if (OUTMODE == 2) {
                        ((short*)outp)[(size_t)(r >> 2) * ldo + c * 4 + (r & 3)] = f2bf(v);
                    } else if (OUTMODE == 5) {
                        ((short*)outp)[blockIdx.z * spitch + (size_t)r * ldo + c] = f2bf(v);
                    } else if (OUTMODE == 3) {
                        sq[i][rr] += v * v;
                        int s = r & 1023, bb = r >> 10;
                        if (c < 768) {
                            ((short*)outp)[(size_t)r * 768 + c] = f2bf(v);
                        } else if (c < 1536) {
                            int df = c - 768; int hh = df >> 6, d = df & 63;
                            int bh2 = bb * 12 + hh;
                            size_t idx = ((size_t)(bh2 * 64 + (s >> 4)) * 2 + (d >> 5)) * 512
                                       + (size_t)((d >> 3) & 3) * 128 + (size_t)(s & 15) * 8 + (d & 7);
                            Kfp[idx] = f2bf(v);
                        } else {
                            int df = c - 1536; int hh = df >> 6, d = df & 63;
                            int bh2 = bb * 12 + hh;
                            size_t idx = ((size_t)(bh2 * 32 + (s >> 5))) * 2048
                                       + (size_t)(d >> 4) * 512 + (size_t)((s >> 3) & 3) * 128
                                       + (size_t)(d & 15) * 8 + (s & 7);
                            Vfp[idx] = f2bf(v);
                        }
                    }
                }
            }
        }
    }

    if constexpr (OUTMODE == 3) {
        // fp32 row-norm side outputs. Each wave's 64-col span [cb, cb+64)
        // is exactly one (matrix, head) group (col0, wc multiples of 64).
        int cb = col0 + wc;
        if (cb < 1536) {
            float* dst = (cb < 768) ? qnG : knG;
            int hh = ((cb < 768) ? cb : cb - 768) >> 6;
#pragma unroll
            for (int i = 0; i < MI; i++) {
#pragma unroll
                for (int rr = 0; rr < 4; rr++) {
                    float s = sq[i][rr];
                    s += __shfl_xor(s, 1);
                    s += __shfl_xor(s, 2);
                    s += __shfl_xor(s, 4);
                    s += __shfl_xor(s, 8);
                    if (ml == 0) {
                        int r = row0 + wr + i * 16 + kq * 4 + rr;
                        int bb = r >> 10, sidx = r & 1023;
                        dst[(size_t)(bb * 12 + hh) * 1024 + sidx] = s;
                    }
                }
            }
        }
    }
}

// ---------------- split-K reduce kernels -----------------------------------

// Wo partials (4, bf16) + bo + residual x -> x2 fp32, then LN(ln2) -> y bf16
__global__ __launch_bounds__(256) void reduce_wo_ln(
        const short* __restrict__ part, const float* __restrict__ bo,
        const float* __restrict__ x, const float* __restrict__ w,
        const float* __restrict__ bvec, float* __restrict__ x2,
        short* __restrict__ y) {
    __shared__ float red[4];
    int row = blockIdx.x, tid = threadIdx.x;
    const size_t SP = (size_t)2048 * 768;
    const short* pr = part + (size_t)row * 768;
    const float* xr = x + (size_t)row * 768;
    float* x2r = x2 + (size_t)row * 768;
    float v[3];
#pragma unroll
    for (int u = 0; u < 3; u++) {
        int c = tid + u * 256;
        float s = bo[c] + xr[c];
#pragma unroll
        for (int z = 0; z < 4; z++) s += bf2f(pr[z * SP + c]);
        v[u] = s; x2r[c] = s;
    }
    float s = block_reduce_sum(v[0] + v[1] + v[2], red);
    float mu = s * (1.0f / 768.f);
    float d0 = v[0] - mu, d1 = v[1] - mu, d2 = v[2] - mu;
    float var = block_reduce_sum(d0 * d0 + d1 * d1 + d2 * d2, red) * (1.0f / 768.f);
    float rs = rsqrtf(var + 1e-5f);
    short* orow = y + (size_t)row * 768;
    orow[tid]       = f2bf(d0 * rs * w[tid]       + bvec[tid]);
    orow[tid + 256] = f2bf(d1 * rs * w[tid + 256] + bvec[tid + 256]);
    orow[tid + 512] = f2bf(d2 * rs * w[tid + 512] + bvec[tid + 512]);
}

// fc1 partials (4, bf16 [2048][768], cols 0..767) + bias -> expanded slices.
// Cols 768..770 computed here as block-reduced dots y[r].fc1_W[768+k] so the
// fc1 GEMM runs an exact 768-block grid. Avqc[(r*4+q)][m] = h1[r][m+q].
__global__ __launch_bounds__(256) void reduce_fc1_expand(
        const short* __restrict__ part, const float* __restrict__ b,
        const short* __restrict__ y, const short* __restrict__ w768,
        short* __restrict__ Avqc) {
    __shared__ float row[772];
    __shared__ float red[4];
    int r = blockIdx.x, tid = threadIdx.x;
    const size_t SP = (size_t)2048 * 768;
    const short* pr = part + (size_t)r * 768;
#pragma unroll
    for (int u = 0; u < 3; u++) {
        int c = tid + u * 256;
        float s = b[c];
#pragma unroll
        for (int z = 0; z < 4; z++) s += bf2f(pr[z * SP + c]);
        row[c] = s;
    }
    const short* yr = y + (size_t)r * 768;
    float y0 = bf2f(yr[tid]), y1 = bf2f(yr[tid + 256]), y2 = bf2f(yr[tid + 512]);
#pragma unroll
    for (int k = 0; k < 3; k++) {
        const short* wk = w768 + k * 768;
        float s = y0 * bf2f(wk[tid]) + y1 * bf2f(wk[tid + 256]) + y2 * bf2f(wk[tid + 512]);
        s = block_reduce_sum(s, red);
        if (tid == 0) row[768 + k] = s + b[768 + k];
    }
    __syncthreads();
#pragma unroll
    for (int q = 0; q < 4; q++) {
        short* orow = Avqc + (size_t)(r * 4 + q) * 768;
#pragma unroll
        for (int u = 0; u < 3; u++) {
            int m = tid + u * 256;
            orow[m] = f2bf(row[m + q]);
        }
    }
}

// fc2 partials (4, bf16) + bias + residual x2 -> out fp32
__global__ __launch_bounds__(256) void reduce_fc2(
        const short* __restrict__ part, const float* __restrict__ b,
        const float* __restrict__ x2, float* __restrict__ out) {
    int t = blockIdx.x * 256 + threadIdx.x;
    int row = t / 192;
    int c = (t - row * 192) * 4;
    size_t off = (size_t)row * 768 + c;
    const size_t SP = (size_t)2048 * 768;
    float4 bb = *(const float4*)(b + c);
    float4 xx = *(const float4*)(x2 + off);
    float o0 = bb.x + xx.x, o1 = bb.y + xx.y, o2 = bb.z + xx.z, o3 = bb.w + xx.w;
#pragma unroll
    for (int z = 0; z < 4; z++) {
        short4 v = *(const short4*)(part + z * SP + off);
        o0 += bf2f(v.x); o1 += bf2f(v.y); o2 += bf2f(v.z); o3 += bf2f(v.w);
    }
    float4 o = make_float4(o0, o1, o2, o3);
    *(float4*)(out + off) = o;
}

// ---------------- MFMA fused attention, INTRA-BLOCK KV-split ---------------
// R19 (kept; R21's V-direct reverted after correctness failure): SWAPPED-
// OPERAND QK (T12 trick). mfma(bk, aq) computes K.Q^T with zero
// rearrangement: C[row=k=kq*4+r][col=q=ml]. Each lane holds P for one q-row
// at 4 consecutive k -> cvt_pk_bf16 pairs + one b64 store replace 8 scalar
// f2bf chains + 8 scattered b16 stores per jtl. Base structure = R4
// measured-best (staged K/V, norm tables, XCD swizzle).

__global__ __launch_bounds__(256) void attn_mfma(
        const short* __restrict__ Qb,    // [2048][768] bf16
        const short* __restrict__ Kf,    // frag-major
        const short* __restrict__ Vf,    // frag-major
        const float* __restrict__ pond,
        const float* __restrict__ qnG,   // [24][1024] fp32 |q|^2
        const float* __restrict__ knG,   // [24][1024] fp32 |k|^2
        short* __restrict__ vals) {      // [2048][768] bf16
    __shared__ __align__(16) short Kt[2 * 4096];   // [wp][tile]; reused as combine buf
    __shared__ __align__(16) short Vt[2 * 4096];
    __shared__ float esx[2][16], rsx[2][16];
    __shared__ __align__(16) short Pe[4 * 16 * 72];
    __shared__ __align__(16) short Pr[4 * 16 * 72];

    const int tid = threadIdx.x;
    const int lane = tid & 63;
    const int wave = tid >> 6;
    const int wq = wave & 1;       // q sub-tile
    const int wp = wave >> 1;      // KV half
    const int ml = lane & 15;
    const int kq = lane >> 4;

    // XCD-affinity swizzle (768 = 8 XCDs x 96 -> bijective)
    const int fid = blockIdx.x;
    const int w = (fid & 7) * 96 + (fid >> 3);
    const int qt2 = w & 31;
    const int bh = w >> 5;          // 0..23
    const int b = (bh >= 12) ? 1 : 0;
    const int h = bh - b * 12;

    const int qrow = b * S_LEN + qt2 * 32 + wq * 16 + ml;
    const short* qp = Qb + (size_t)qrow * 768 + h * 64 + kq * 8;
    bf16x8 aq0 = *(const bf16x8*)qp;
    bf16x8 aq1 = *(const bf16x8*)(qp + 32);

    // scalar q-norm for this lane's q-row (q = ml)
    const float* qnB = qnG + (size_t)bh * 1024 + qt2 * 32 + wq * 16;
    float qn_l = qnB[ml];
    float is_l = 1.0f / fminf(fmaxf(qn_l, 1e-8f), 1e4f);
    const float* knB = knG + (size_t)bh * 1024;

    f32x4 Oe[4], Or[4];
#pragma unroll
    for (int dt = 0; dt < 4; dt++) { Oe[dt] = {0.f,0.f,0.f,0.f}; Or[dt] = {0.f,0.f,0.f,0.f}; }
    float es_l = 0.f, rs_l = 0.f;

    const short* KfB = Kf + (size_t)bh * 65536;
    const short* VfB = Vf + (size_t)bh * 65536;
    short* PeW = Pe + wave * 1152;
    short* PrW = Pr + wave * 1152;
    const short* KtW = Kt + wp * 4096;
    const short* VtW = Vt + wp * 4096;

    for (int it = 0; it < 8; it++) {
        __syncthreads();   // all waves done reading prior tiles
        {
            const short* sk0 = KfB + it * 4096 + tid * 8;
            gld_lds16(Kt + tid * 8, sk0);
            gld_lds16(Kt + 2048 + tid * 8, sk0 + 2048);
            const short* sk1 = KfB + (it + 8) * 4096 + tid * 8;
            gld_lds16(Kt + 4096 + tid * 8, sk1);
            gld_lds16(Kt + 6144 + tid * 8, sk1 + 2048);
            const short* sv0 = VfB + it * 4096 + tid * 8;
            gld_lds16(Vt + tid * 8, sv0);
            gld_lds16(Vt + 2048 + tid * 8, sv0 + 2048);
            const short* sv1 = VfB + (it + 8) * 4096 + tid * 8;
            gld_lds16(Vt + 4096 + tid * 8, sv1);
            gld_lds16(Vt + 6144 + tid * 8, sv1 + 2048);
        }
        // k-norms for this wave's tile (4 consecutive per lane per jtl);
        // loads land under the barrier's vmcnt drain
        float4 kn4[4];
        {
            const float* knI = knB + (it + 8 * wp) * 64;
#pragma unroll
            for (int jtl = 0; jtl < 4; jtl++)
                kn4[jtl] = *(const float4*)(knI + jtl * 16 + kq * 4);
        }
        __syncthreads();   // tiles resident

#pragma unroll
        for (int jtl = 0; jtl < 4; jtl++) {
            bf16x8 bk0 = *(const bf16x8*)&KtW[(jtl * 2 + 0) * 512 + lane * 8];
            bf16x8 bk1 = *(const bf16x8*)&KtW[(jtl * 2 + 1) * 512 + lane * 8];
            // swapped operands: C[row=k=kq*4+r][col=q=ml]
            f32x4 c = {0.f,0.f,0.f,0.f};
            c = __builtin_amdgcn_mfma_f32_16x16x32_bf16(bk0, aq0, c, 0, 0, 0);
            c = __builtin_amdgcn_mfma_f32_16x16x32_bf16(bk1, aq1, c, 0, 0, 0);
            float kna[4] = {kn4[jtl].x, kn4[jtl].y, kn4[jtl].z, kn4[jtl].w};
            float e[4], rb[4];
#pragma unroll
            for (int r = 0; r < 4; r++) {
                float qk = c[r];
                e[r] = __expf(qk * 0.125f);
                float tt = (2.f * qk - qn_l - kna[r]) * is_l;
                rb[r] = fminf(__expf(tt), 1.0f);
                es_l += e[r]; rs_l += rb[r];
            }
            // pack 4 consecutive-k P values -> one b64 store per matrix
            uint2 pe = make_uint2(cvt_pk_bf16(e[0], e[1]), cvt_pk_bf16(e[2], e[3]));
            uint2 pr = make_uint2(cvt_pk_bf16(rb[0], rb[1]), cvt_pk_bf16(rb[2], rb[3]));
            *(uint2*)&PeW[ml * 72 + jtl * 16 + kq * 4] = pe;
            *(uint2*)&PrW[ml * 72 + jtl * 16 + kq * 4] = pr;
        }
        // (no barrier: P round-trip is wave-local)

#pragma unroll
        for (int jcl = 0; jcl < 2; jcl++) {
            bf16x8 pa_e = *(const bf16x8*)&PeW[ml * 72 + jcl * 32 + kq * 8];
            bf16x8 pa_r = *(const bf16x8*)&PrW[ml * 72 + jcl * 32 + kq * 8];
#pragma unroll
            for (int dt = 0; dt < 4; dt++) {
                bf16x8 bv = *(const bf16x8*)&VtW[(jcl * 4 + dt) * 512 + lane * 8];
                Oe[dt] = __builtin_amdgcn_mfma_f32_16x16x32_bf16(pa_e, bv, Oe[dt], 0, 0, 0);
                Or[dt] = __builtin_amdgcn_mfma_f32_16x16x32_bf16(pa_r, bv, Or[dt], 0, 0, 0);
            }
        }
    }

    // es/rs: sum the 4 kq copies of each q=ml row
    es_l += __shfl_xor(es_l, 16);
    es_l += __shfl_xor(es_l, 32);
    rs_l += __shfl_xor(rs_l, 16);
    rs_l += __shfl_xor(rs_l, 32);

    // cross-half combine in LDS (Kt region is dead after the loop)
    __syncthreads();                     // everyone past the last QK read of Kt
    float* cb = (float*)Kt;              // 16 KB: [wq*64+lane][32]
    if (wp == 1) {
        float* cl = cb + (size_t)(wq * 64 + lane) * 32;
#pragma unroll
        for (int dt = 0; dt < 4; dt++)
#pragma unroll
            for (int r = 0; r < 4; r++) {
                cl[dt * 4 + r] = Oe[dt][r];
                cl[16 + dt * 4 + r] = Or[dt][r];
            }
        if (kq == 0) {
            esx[wq][ml] = es_l;
            rsx[wq][ml] = rs_l;
        }
    }
    __syncthreads();
    if (wp == 0) {
        float p = pond[0];
        float sv = 1.0f / (1.0f + __expf(-p));
        float p0 = 1.0f - sv, p1 = sv;
        float blendinv = 1.0f / (p0 + p1 + 1e-7f);
        // per-lane totals for q = ml, then redistribute to q = kq*4+r
        float es_q = es_l + esx[wq][ml];
        float rs_q = rs_l + rsx[wq][ml];
        const float* cl = cb + (size_t)(wq * 64 + lane) * 32;
        float we[4], wr[4];
#pragma unroll
        for (int r = 0; r < 4; r++) {
            float es = __shfl(es_q, kq * 4 + r);
            float rs = __shfl(rs_q, kq * 4 + r);
            we[r] = p0 * blendinv / es;
            wr[r] = p1 * blendinv / fmaxf(rs, 1e-8f);
        }
#pragma unroll
        for (int dt = 0; dt < 4; dt++) {
#pragma unroll
            for (int r = 0; r < 4; r++) {
                float oe = Oe[dt][r] + cl[dt * 4 + r];
                float orr = Or[dt][r] + cl[16 + dt * 4 + r];
                float v = oe * we[r] + orr * wr[r];
                int token = b * S_LEN + qt2 * 32 + wq * 16 + kq * 4 + r;
                vals[(size_t)token * 768 + h * 64 + dt * 16 + ml] = f2bf(v);
            }
        }
    }
}

// ---------------- launcher -------------------------------------------------

extern "C" void kernel_launch(void* const* d_in, const int* in_sizes, int n_in,
                              void* d_out, int out_size, void* d_ws, size_t ws_size,
                              hipStream_t stream) {
    const float* x     = (const float*)d_in[0];
    const float* ln1_w = (const float*)d_in[1];
    const float* ln1_b = (const float*)d_in[2];
    const float* Wq    = (const float*)d_in[3];
    const float* bq    = (const float*)d_in[4];
    const float* Wk    = (const float*)d_in[5];
    const float* bk    = (const float*)d_in[6];
    const float* Wv    = (const float*)d_in[7];
    const float* bv    = (const float*)d_in[8];
    const float* Wo    = (const float*)d_in[9];
    const float* bo    = (const float*)d_in[10];
    const float* pond  = (const float*)d_in[11];
    const float* ln2_w = (const float*)d_in[12];
    const float* ln2_b = (const float*)d_in[13];
    const float* fc1_W = (const float*)d_in[14];
    const float* fc1_b = (const float*)d_in[15];
    const float* vqc_W = (const float*)d_in[16];
    const float* vqc_b = (const float*)d_in[17];
    const float* fc2_W = (const float*)d_in[18];
    const float* fc2_b = (const float*)d_in[19];
    float* out = (float*)d_out;

    char* p = (char*)d_ws;
    short* Qb   = (short*)p;  p += (size_t)2048 * 768 * 2;
    short* Kfb  = (short*)p;  p += (size_t)2048 * 768 * 2;
    short* Vfb  = (short*)p;  p += (size_t)2048 * 768 * 2;
    float* x2   = (float*)p;  p += (size_t)2048 * 768 * 4;
    float* bqkv = (float*)p;  p += 2304 * 4;
    float* qnG  = (float*)p;  p += (size_t)24 * 1024 * 4;
    float* knG  = (float*)p;  p += (size_t)24 * 1024 * 4;
    short* actb = (short*)p;  p += (size_t)2048 * 768 * 2;
    short* g    = (short*)p;  p += (size_t)2048 * 3072 * 2;
    short* Avqc = (short*)p;  p += (size_t)8192 * 768 * 2;
    short* partb = (short*)p; p += (size_t)4 * 2048 * 768 * 2;   // 12.6 MB split-K partials
    short* wreg = (short*)p;  p += (size_t)5900544 * 2;
    short* Wqkvb = wreg;
    short* Wob   = wreg + 1769472;
    short* fc1b  = wreg + 2359296;
    short* vqcb  = wreg + 2951424;
    short* fc2b  = wreg + 3541248;

    dim3 blk(256);
    const size_t SP = (size_t)2048 * 768;

    // 0. preamble: ln1 + bias concat + QKV weight conversion only (3777 blocks)
    preamble<<<3777, blk, 0, stream>>>(Wq, Wk, Wv, Wo, fc1_W, vqc_W, fc2_W, wreg,
                                       bq, bk, bv, bqkv, x, ln1_w, ln1_b, actb);
    // 1. fused QKV projection (576 GEMM blocks) + qn/kn side outputs
    //    + 1026 appended converter blocks (y >= 32, dispatched last)
    gemm_bf16<3, 64><<<dim3(18, 89, 1), blk, 0, stream>>>(actb, 768, Wqkvb, 768, bqkv,
                                                          Qb, 768, 0, Kfb, Vfb, 2304, 768, 0,
                                                          qnG, knG,
                                                          Wo, fc1_W, vqc_W, fc2_W, wreg);
    // 2. MFMA attention (R4 structure + swapped-QK in-lane P), 768 blocks (3/CU)
    attn_mfma<<<768, blk, 0, stream>>>(Qb, Kfb, Vfb, pond, qnG, knG, actb);
    // 3. Wo split-K x4 (768 blocks = 3/CU)
    gemm_bf16<5, 64><<<dim3(6, 32, 4), blk, 0, stream>>>(actb, 768, Wob, 768, nullptr,
                                                         partb, 768, SP,
                                                         nullptr, nullptr, 768, 192, 0,
                                                         nullptr, nullptr,
                                                         nullptr, nullptr, nullptr, nullptr, nullptr);
    // 4. reduce + bo + residual(x) -> x2 fp32, fused ln2 -> actb
    reduce_wo_ln<<<2048, blk, 0, stream>>>(partb, bo, x, ln2_w, ln2_b, x2, actb);
    // 5. fc1 split-K x4, cols 0..767 only (768 blocks = 3/CU exact)
    gemm_bf16<5, 64><<<dim3(6, 32, 4), blk, 0, stream>>>(actb, 768, fc1b, 768, nullptr,
                                                         partb, 768, SP,
                                                         nullptr, nullptr, 768, 192, 0,
                                                         nullptr, nullptr,
                                                         nullptr, nullptr, nullptr, nullptr, nullptr);
    // 6. reduce + bias + cols 768..770 dots + expand -> Avqc [8192][768]
    reduce_fc1_expand<<<2048, blk, 0, stream>>>(partb, fc1_b, actb, fc1b + 768 * 768, Avqc);
    // 7. vqc (direct) + bias + gelu + transpose scatter (768 blocks = 3/CU)
    gemm_bf16<2, 64><<<dim3(6, 128, 1), blk, 0, stream>>>(Avqc, 768, vqcb, 768, vqc_b,
                                                          g, 3072, 0, nullptr, nullptr, 768, 768, 1,
                                                          nullptr, nullptr,
                                                          nullptr, nullptr, nullptr, nullptr, nullptr);
    // 8. fc2 split-K x4 (768 blocks = 3/CU)
    gemm_bf16<5, 64><<<dim3(6, 32, 4), blk, 0, stream>>>(g, 3072, fc2b, 3072, nullptr,
                                                         partb, 768, SP,
                                                         nullptr, nullptr, 768, 768, 0,
                                                         nullptr, nullptr,
                                                         nullptr, nullptr, nullptr, nullptr, nullptr);
    // 9. reduce + bias + residual(x2) -> out fp32
    reduce_fc2<<<1536, blk, 0, stream>>>(partb, fc2_b, x2, out);
}

// Round 12
// 145.084 us; speedup vs baseline: 1.0150x; 1.0150x over previous
//
#include <hip/hip_runtime.h>
#include <math.h>

#define E_DIM 768
#define S_LEN 1024
#define B_SZ 2
#define H_CNT 12
#define D_HEAD 64
#define M_DIM 768
#define Q_STRIDE 4
#define N_FC1 771            // only M+Q-1 columns of fc1 are consumed

typedef __attribute__((ext_vector_type(8))) short bf16x8;
typedef __attribute__((ext_vector_type(4))) float f32x4;

#define AS1 __attribute__((address_space(1)))
#define AS3 __attribute__((address_space(3)))

__device__ __forceinline__ void gld_lds16(void* lds, const void* g) {
    __builtin_amdgcn_global_load_lds((const AS1 void*)g, (AS3 void*)lds, 16, 0, 0);
}

__device__ __forceinline__ short f2bf(float f) {
    unsigned u = __float_as_uint(f);
    unsigned r = (u + 0x7fffu + ((u >> 16) & 1u)) >> 16;
    return (short)r;
}

__device__ __forceinline__ float bf2f(short s) {
    return __uint_as_float(((unsigned)(unsigned short)s) << 16);
}

// pack two f32 -> one dword of 2 bf16 (RNE), single instruction
__device__ __forceinline__ unsigned cvt_pk_bf16(float lo, float hi) {
    unsigned r;
    asm("v_cvt_pk_bf16_f32 %0, %1, %2" : "=v"(r) : "v"(lo), "v"(hi));
    return r;
}

// ---------------- block reduction helper (256 threads, 4 waves) ------------

__device__ __forceinline__ float block_reduce_sum(float v, volatile float* red) {
#pragma unroll
    for (int off = 32; off > 0; off >>= 1) v += __shfl_xor(v, off);
    __syncthreads();
    if ((threadIdx.x & 63) == 0) red[threadIdx.x >> 6] = v;
    __syncthreads();
    return red[0] + red[1] + red[2] + red[3];
}

// ------------- preamble: ln1 + bias concat + QKV weight conversion --------
// R20: preamble converts ONLY the QKV weights; Wo/fc1/vqc/fc2 conversion is
// backfilled into the QKV GEMM dispatch (see gemm_bf16 OUTMODE==3).

__global__ __launch_bounds__(256) void preamble(
        const float* __restrict__ Wq, const float* __restrict__ Wk,
        const float* __restrict__ Wv, const float* __restrict__ Wo,
        const float* __restrict__ fc1W, const float* __restrict__ vqcW,
        const float* __restrict__ fc2W, short* __restrict__ dst,
        const float* __restrict__ bq, const float* __restrict__ bk,
        const float* __restrict__ bv, float* __restrict__ bqkv,
        const float* __restrict__ x, const float* __restrict__ ln1_w,
        const float* __restrict__ ln1_b, short* __restrict__ actb) {
    __shared__ float red[4];
    int tid = threadIdx.x;
    if (blockIdx.x < 2048) {          // ln1
        int row = blockIdx.x;
        const float* xr = x + (size_t)row * E_DIM;
        float v0 = xr[tid], v1 = xr[tid + 256], v2 = xr[tid + 512];
        float s = block_reduce_sum(v0 + v1 + v2, red);
        float mu = s * (1.0f / E_DIM);
        float d0 = v0 - mu, d1 = v1 - mu, d2 = v2 - mu;
        float var = block_reduce_sum(d0 * d0 + d1 * d1 + d2 * d2, red) * (1.0f / E_DIM);
        float rs = rsqrtf(var + 1e-5f);
        short* orow = actb + (size_t)row * E_DIM;
        orow[tid]       = f2bf(d0 * rs * ln1_w[tid]       + ln1_b[tid]);
        orow[tid + 256] = f2bf(d1 * rs * ln1_w[tid + 256] + ln1_b[tid + 256]);
        orow[tid + 512] = f2bf(d2 * rs * ln1_w[tid + 512] + ln1_b[tid + 512]);
        return;
    }
    if (blockIdx.x == 2048) {         // bias concat
#pragma unroll
        for (int u = 0; u < 9; u++) {
            int i = tid + u * 256;
            float v = (i < 768) ? bq[i] : (i < 1536) ? bk[i - 768] : bv[i - 1536];
            bqkv[i] = v;
        }
        return;
    }
    int t = (blockIdx.x - 2049) * 256 + tid;      // float4 index
    if (t >= 442368) return;                      // QKV weights only: 1769472 / 4
    int e = t * 4;
    const float* src; int off;
    if      (e < 589824)  { src = Wq;   off = e; }
    else if (e < 1179648) { src = Wk;   off = e - 589824; }
    else                  { src = Wv;   off = e - 1179648; }
    float4 v = *(const float4*)(src + off);
    short4 o = make_short4(f2bf(v.x), f2bf(v.y), f2bf(v.z), f2bf(v.w));
    *(short4*)(dst + e) = o;
}

// ---------------- bf16 MFMA NT GEMM (BK=64, double-buffered, MR-templated) -
// MR x 128 tile, BK=64 (two MRx32 sub-slabs), double-buffered (one barrier
// per iteration). LDS 48 KB at MR=64 -> 3 blocks/CU, matching 768-block
// balanced grids (R10). R18/R7 lesson: MR=128 shrinks grids to 288-384
// blocks = 1.1-1.5/CU -> grid imbalance costs more than the tile wins.
// OUTMODE: 2 = bias+GELU+bf16 transpose-scatter (vqc); 3 = QKV split
//          (+ fp32 q/k row-norm side outputs qnG/knG; + R20 appended
//          weight-converter blocks at blockIdx.y >= 32); 5 = bf16 partial.

template <int OUTMODE, int MR>
__global__ __launch_bounds__(256, 2) void gemm_bf16(
        const short* __restrict__ A, int lda,
        const short* __restrict__ W, int ldw,
        const float* __restrict__ bias,
        void* __restrict__ outp, int ldo, size_t spitch,
        short* __restrict__ Kfp, short* __restrict__ Vfp,
        int N, int klen, int dogelu,
        float* __restrict__ qnG, float* __restrict__ knG,
        const float* __restrict__ cW0, const float* __restrict__ cW1,
        const float* __restrict__ cW2, const float* __restrict__ cW3,
        short* __restrict__ cdst) {
    if constexpr (OUTMODE == 3) {
        // appended weight-converter blocks (dispatched last: y >= 32)
        if (blockIdx.y >= 32) {
            int cid = (blockIdx.y - 32) * 18 + blockIdx.x;
            int tid = threadIdx.x;
#pragma unroll
            for (int u = 0; u < 4; u++) {
                int t = cid * 1024 + u * 256 + tid;   // float4 idx in remaining region
                if (t < 1032768) {
                    int e = 1769472 + t * 4;          // global float idx
                    const float* src; int off;
                    if      (e < 2359296) { src = cW0; off = e - 1769472; }  // Wo
                    else if (e < 2951424) { src = cW1; off = e - 2359296; }  // fc1
                    else if (e < 3541248) { src = cW2; off = e - 2951424; }  // vqc
                    else                  { src = cW3; off = e - 3541248; }  // fc2
                    float4 v = *(const float4*)(src + off);
                    short4 o = make_short4(f2bf(v.x), f2bf(v.y), f2bf(v.z), f2bf(v.w));
                    *(short4*)(cdst + e) = o;
                }
            }
            return;
        }
    }
    constexpr int MI = MR / 32;
    constexpr int AH = MR * 32;
    constexpr int NA = MR / 64;
    constexpr int ASL = 2 * AH;
    __shared__ short At[2 * ASL];
    __shared__ short Bt[2 * 8192];
    const int tid = threadIdx.x;
    const int lane = tid & 63;
    const int wave = tid >> 6;
    const int wr = (wave >> 1) * (MI * 16);
    const int wc = (wave & 1) * 64;
    const int ml = lane & 15;
    const int kq = lane >> 4;
    const int row0 = blockIdx.y * MR;
    const int col0 = blockIdx.x * 128;
    const int kbase = blockIdx.z * klen;

    const short* Ag[NA]; int aoff[NA];
#pragma unroll
    for (int u = 0; u < NA; u++) {
        int c = tid + u * 256;
        int am = c >> 2, ak = ((c & 3) ^ ((am >> 1) & 3)) * 8;
        Ag[u] = A + (size_t)(row0 + am) * lda + ak + kbase;
        aoff[u] = c * 8;
    }
    const int c0 = tid, c1 = tid + 256;
    const int bm0 = c0 >> 2, bk0 = (((c0 & 3) ^ ((bm0 >> 1) & 3))) * 8;
    const int bm1 = c1 >> 2, bk1 = (((c1 & 3) ^ ((bm1 >> 1) & 3))) * 8;
    int wrow0 = col0 + bm0; if (wrow0 > N - 1) wrow0 = N - 1;
    int wrow1 = col0 + bm1; if (wrow1 > N - 1) wrow1 = N - 1;
    const short* Wg0 = W + (size_t)wrow0 * ldw + bk0 + kbase;
    const short* Wg1 = W + (size_t)wrow1 * ldw + bk1 + kbase;

    const int kxor = (kq ^ ((ml >> 1) & 3)) * 8;

    f32x4 acc[MI][4];
#pragma unroll
    for (int i = 0; i < MI; i++)
#pragma unroll
        for (int j = 0; j < 4; j++) acc[i][j] = {0.f, 0.f, 0.f, 0.f};

    auto stage = [&](int buf, int k0) {
        short* Ab = At + buf * ASL;
        short* Bb = Bt + buf * 8192;
#pragma unroll
        for (int u = 0; u < NA; u++) {
            gld_lds16(Ab + aoff[u], Ag[u] + k0);
            gld_lds16(Ab + AH + aoff[u], Ag[u] + k0 + 32);
        }
        gld_lds16(Bb + c0 * 8, Wg0 + k0);
        gld_lds16(Bb + c1 * 8, Wg1 + k0);
        gld_lds16(Bb + 4096 + c0 * 8, Wg0 + k0 + 32);
        gld_lds16(Bb + 4096 + c1 * 8, Wg1 + k0 + 32);
    };

    stage(0, 0);
    int cur = 0;
    for (int k0 = 0; k0 < klen; k0 += 64) {
        __syncthreads();
        if (k0 + 64 < klen) stage(cur ^ 1, k0 + 64);
        const short* Ac = At + cur * ASL;
        const short* Bc = Bt + cur * 8192;
#pragma unroll
        for (int half = 0; half < 2; half++) {
            const short* Ah = Ac + half * AH;
            const short* Bh = Bc + half * 4096;
            bf16x8 af[MI], bfr[4];
#pragma unroll
            for (int i = 0; i < MI; i++)
                af[i] = *(const bf16x8*)&Ah[(wr + i * 16 + ml) * 32 + kxor];
#pragma unroll
            for (int j = 0; j < 4; j++)
                bfr[j] = *(const bf16x8*)&Bh[(wc + j * 16 + ml) * 32 + kxor];
#pragma unroll
            for (int i = 0; i < MI; i++)
#pragma unroll
                for (int j = 0; j < 4; j++)
                    acc[i][j] = __builtin_amdgcn_mfma_f32_16x16x32_bf16(af[i], bfr[j], acc[i][j], 0, 0, 0);
        }
        cur ^= 1;
    }

    // epilogue: C/D layout col = lane&15, row = (lane>>4)*4 + reg
    float sq[MI][4];
    if constexpr (OUTMODE == 3) {
#pragma unroll
        for (int i = 0; i < MI; i++)
#pragma unroll
            for (int rr = 0; rr < 4; rr++) sq[i][rr] = 0.f;
    }
#pragma unroll
    for (int i = 0; i < MI; i++) {
#pragma unroll
        for (int j = 0; j < 4; j++) {
#pragma unroll
            for (int rr = 0; rr < 4; rr++) {
                int r = row0 + wr + i * 16 + kq * 4 + rr;
                int c = col0 + wc + j * 16 + ml;
                if (c < N) {
                    float v = acc[i][j][rr];
                    if (OUTMODE < 4) v += bias[c];
                    if (OUTMODE == 2 && dogelu)
                        v = 0.5f * v * (1.0f + erff(v * 0.70710678118654752f));
                    if (OUTMODE == 2) {
                        ((short*)outp)[(size_t)(r >> 2) * ldo + c * 4 + (r & 3)] = f2bf(v);
                    } else if (OUTMODE == 5) {
                        ((short*)outp)[blockIdx.z * spitch + (size_t)r * ldo + c] = f2bf(v);
                    } else if (OUTMODE == 3) {
                        sq[i][rr] += v * v;
                        int s = r & 1023, bb = r >> 10;
                        if (c < 768) {
                            ((short*)outp)[(size_t)r * 768 + c] = f2bf(v);
                        } else if (c < 1536) {
                            int df = c - 768; int hh = df >> 6, d = df & 63;
                            int bh2 = bb * 12 + hh;
                            size_t idx = ((size_t)(bh2 * 64 + (s >> 4)) * 2 + (d >> 5)) * 512
                                       + (size_t)((d >> 3) & 3) * 128 + (size_t)(s & 15) * 8 + (d & 7);
                            Kfp[idx] = f2bf(v);
                        } else {
                            int df = c - 1536; int hh = df >> 6, d = df & 63;
                            int bh2 = bb * 12 + hh;
                            size_t idx = ((size_t)(bh2 * 32 + (s >> 5))) * 2048
                                       + (size_t)(d >> 4) * 512 + (size_t)((s >> 3) & 3) * 128
                                       + (size_t)(d & 15) * 8 + (s & 7);
                            Vfp[idx] = f2bf(v);
                        }
                    }
                }
            }
        }
    }

    if constexpr (OUTMODE == 3) {
        // fp32 row-norm side outputs. Each wave's 64-col span [cb, cb+64)
        // is exactly one (matrix, head) group (col0, wc multiples of 64).
        int cb = col0 + wc;
        if (cb < 1536) {
            float* dst = (cb < 768) ? qnG : knG;
            int hh = ((cb < 768) ? cb : cb - 768) >> 6;
#pragma unroll
            for (int i = 0; i < MI; i++) {
#pragma unroll
                for (int rr = 0; rr < 4; rr++) {
                    float s = sq[i][rr];
                    s += __shfl_xor(s, 1);
                    s += __shfl_xor(s, 2);
                    s += __shfl_xor(s, 4);
                    s += __shfl_xor(s, 8);
                    if (ml == 0) {
                        int r = row0 + wr + i * 16 + kq * 4 + rr;
                        int bb = r >> 10, sidx = r & 1023;
                        dst[(size_t)(bb * 12 + hh) * 1024 + sidx] = s;
                    }
                }
            }
        }
    }
}

// ---------------- split-K reduce kernels -----------------------------------

// Wo partials (4, bf16) + bo + residual x -> x2 fp32, then LN(ln2) -> y bf16
__global__ __launch_bounds__(256) void reduce_wo_ln(
        const short* __restrict__ part, const float* __restrict__ bo,
        const float* __restrict__ x, const float* __restrict__ w,
        const float* __restrict__ bvec, float* __restrict__ x2,
        short* __restrict__ y) {
    __shared__ float red[4];
    int row = blockIdx.x, tid = threadIdx.x;
    const size_t SP = (size_t)2048 * 768;
    const short* pr = part + (size_t)row * 768;
    const float* xr = x + (size_t)row * 768;
    float* x2r = x2 + (size_t)row * 768;
    float v[3];
#pragma unroll
    for (int u = 0; u < 3; u++) {
        int c = tid + u * 256;
        float s = bo[c] + xr[c];
#pragma unroll
        for (int z = 0; z < 4; z++) s += bf2f(pr[z * SP + c]);
        v[u] = s; x2r[c] = s;
    }
    float s = block_reduce_sum(v[0] + v[1] + v[2], red);
    float mu = s * (1.0f / 768.f);
    float d0 = v[0] - mu, d1 = v[1] - mu, d2 = v[2] - mu;
    float var = block_reduce_sum(d0 * d0 + d1 * d1 + d2 * d2, red) * (1.0f / 768.f);
    float rs = rsqrtf(var + 1e-5f);
    short* orow = y + (size_t)row * 768;
    orow[tid]       = f2bf(d0 * rs * w[tid]       + bvec[tid]);
    orow[tid + 256] = f2bf(d1 * rs * w[tid + 256] + bvec[tid + 256]);
    orow[tid + 512] = f2bf(d2 * rs * w[tid + 512] + bvec[tid + 512]);
}

// fc1 partials (4, bf16 [2048][768], cols 0..767) + bias -> expanded slices.
// Cols 768..770 computed here as block-reduced dots y[r].fc1_W[768+k] so the
// fc1 GEMM runs an exact 768-block grid. Avqc[(r*4+q)][m] = h1[r][m+q].
__global__ __launch_bounds__(256) void reduce_fc1_expand(
        const short* __restrict__ part, const float* __restrict__ b,
        const short* __restrict__ y, const short* __restrict__ w768,
        short* __restrict__ Avqc) {
    __shared__ float row[772];
    __shared__ float red[4];
    int r = blockIdx.x, tid = threadIdx.x;
    const size_t SP = (size_t)2048 * 768;
    const short* pr = part + (size_t)r * 768;
#pragma unroll
    for (int u = 0; u < 3; u++) {
        int c = tid + u * 256;
        float s = b[c];
#pragma unroll
        for (int z = 0; z < 4; z++) s += bf2f(pr[z * SP + c]);
        row[c] = s;
    }
    const short* yr = y + (size_t)r * 768;
    float y0 = bf2f(yr[tid]), y1 = bf2f(yr[tid + 256]), y2 = bf2f(yr[tid + 512]);
#pragma unroll
    for (int k = 0; k < 3; k++) {
        const short* wk = w768 + k * 768;
        float s = y0 * bf2f(wk[tid]) + y1 * bf2f(wk[tid + 256]) + y2 * bf2f(wk[tid + 512]);
        s = block_reduce_sum(s, red);
        if (tid == 0) row[768 + k] = s + b[768 + k];
    }
    __syncthreads();
#pragma unroll
    for (int q = 0; q < 4; q++) {
        short* orow = Avqc + (size_t)(r * 4 + q) * 768;
#pragma unroll
        for (int u = 0; u < 3; u++) {
            int m = tid + u * 256;
            orow[m] = f2bf(row[m + q]);
        }
    }
}

// fc2 partials (4, bf16) + bias + residual x2 -> out fp32
__global__ __launch_bounds__(256) void reduce_fc2(
        const short* __restrict__ part, const float* __restrict__ b,
        const float* __restrict__ x2, float* __restrict__ out) {
    int t = blockIdx.x * 256 + threadIdx.x;
    int row = t / 192;
    int c = (t - row * 192) * 4;
    size_t off = (size_t)row * 768 + c;
    const size_t SP = (size_t)2048 * 768;
    float4 bb = *(const float4*)(b + c);
    float4 xx = *(const float4*)(x2 + off);
    float o0 = bb.x + xx.x, o1 = bb.y + xx.y, o2 = bb.z + xx.z, o3 = bb.w + xx.w;
#pragma unroll
    for (int z = 0; z < 4; z++) {
        short4 v = *(const short4*)(part + z * SP + off);
        o0 += bf2f(v.x); o1 += bf2f(v.y); o2 += bf2f(v.z); o3 += bf2f(v.w);
    }
    float4 o = make_float4(o0, o1, o2, o3);
    *(float4*)(out + off) = o;
}

// ---------------- MFMA fused attention, INTRA-BLOCK KV-split ---------------
// R22: two low-risk tweaks on the banked R19 structure:
//  (a) T5 s_setprio(1) around the QK/softmax/PV compute phase. m190/m191
//      rule: null on barrier-lockstep grids, +4-7% when independent blocks
//      co-resident on a CU sit at different phases -- here 3 independent
//      blocks/CU. Compute-phase waves preempt other blocks' staging waves.
//  (b) exp -> exp2 with log2e folded into the softmax scale and is_l:
//      deletes one dependent v_mul per exp (32/lane/iter) from the serial
//      QK->softmax chain. Mathematically identical (constant reassoc).
// R19: swapped-operand QK (mfma(bk,aq) -> C[k][q]), cvt_pk P-pack, one b64
// store per jtl. Base = R4 measured-best (staged K/V, norm tables, swizzle).

#define LOG2E 1.44269504088896340736f

__global__ __launch_bounds__(256) void attn_mfma(
        const short* __restrict__ Qb,    // [2048][768] bf16
        const short* __restrict__ Kf,    // frag-major
        const short* __restrict__ Vf,    // frag-major
        const float* __restrict__ pond,
        const float* __restrict__ qnG,   // [24][1024] fp32 |q|^2
        const float* __restrict__ knG,   // [24][1024] fp32 |k|^2
        short* __restrict__ vals) {      // [2048][768] bf16
    __shared__ __align__(16) short Kt[2 * 4096];   // [wp][tile]; reused as combine buf
    __shared__ __align__(16) short Vt[2 * 4096];
    __shared__ float esx[2][16], rsx[2][16];
    __shared__ __align__(16) short Pe[4 * 16 * 72];
    __shared__ __align__(16) short Pr[4 * 16 * 72];

    const int tid = threadIdx.x;
    const int lane = tid & 63;
    const int wave = tid >> 6;
    const int wq = wave & 1;       // q sub-tile
    const int wp = wave >> 1;      // KV half
    const int ml = lane & 15;
    const int kq = lane >> 4;

    // XCD-affinity swizzle (768 = 8 XCDs x 96 -> bijective)
    const int fid = blockIdx.x;
    const int w = (fid & 7) * 96 + (fid >> 3);
    const int qt2 = w & 31;
    const int bh = w >> 5;          // 0..23
    const int b = (bh >= 12) ? 1 : 0;
    const int h = bh - b * 12;

    const int qrow = b * S_LEN + qt2 * 32 + wq * 16 + ml;
    const short* qp = Qb + (size_t)qrow * 768 + h * 64 + kq * 8;
    bf16x8 aq0 = *(const bf16x8*)qp;
    bf16x8 aq1 = *(const bf16x8*)(qp + 32);

    // scalar q-norm for this lane's q-row (q = ml); log2e folded into is2
    const float* qnB = qnG + (size_t)bh * 1024 + qt2 * 32 + wq * 16;
    float qn_l = qnB[ml];
    float is2_l = LOG2E / fminf(fmaxf(qn_l, 1e-8f), 1e4f);
    const float* knB = knG + (size_t)bh * 1024;

    f32x4 Oe[4], Or[4];
#pragma unroll
    for (int dt = 0; dt < 4; dt++) { Oe[dt] = {0.f,0.f,0.f,0.f}; Or[dt] = {0.f,0.f,0.f,0.f}; }
    float es_l = 0.f, rs_l = 0.f;

    const short* KfB = Kf + (size_t)bh * 65536;
    const short* VfB = Vf + (size_t)bh * 65536;
    short* PeW = Pe + wave * 1152;
    short* PrW = Pr + wave * 1152;
    const short* KtW = Kt + wp * 4096;
    const short* VtW = Vt + wp * 4096;

    for (int it = 0; it < 8; it++) {
        __syncthreads();   // all waves done reading prior tiles
        {
            const short* sk0 = KfB + it * 4096 + tid * 8;
            gld_lds16(Kt + tid * 8, sk0);
            gld_lds16(Kt + 2048 + tid * 8, sk0 + 2048);
            const short* sk1 = KfB + (it + 8) * 4096 + tid * 8;
            gld_lds16(Kt + 4096 + tid * 8, sk1);
            gld_lds16(Kt + 6144 + tid * 8, sk1 + 2048);
            const short* sv0 = VfB + it * 4096 + tid * 8;
            gld_lds16(Vt + tid * 8, sv0);
            gld_lds16(Vt + 2048 + tid * 8, sv0 + 2048);
            const short* sv1 = VfB + (it + 8) * 4096 + tid * 8;
            gld_lds16(Vt + 4096 + tid * 8, sv1);
            gld_lds16(Vt + 6144 + tid * 8, sv1 + 2048);
        }
        // k-norms for this wave's tile (4 consecutive per lane per jtl);
        // loads land under the barrier's vmcnt drain
        float4 kn4[4];
        {
            const float* knI = knB + (it + 8 * wp) * 64;
#pragma unroll
            for (int jtl = 0; jtl < 4; jtl++)
                kn4[jtl] = *(const float4*)(knI + jtl * 16 + kq * 4);
        }
        __syncthreads();   // tiles resident

        __builtin_amdgcn_s_setprio(1);
#pragma unroll
        for (int jtl = 0; jtl < 4; jtl++) {
            bf16x8 bk0 = *(const bf16x8*)&KtW[(jtl * 2 + 0) * 512 + lane * 8];
            bf16x8 bk1 = *(const bf16x8*)&KtW[(jtl * 2 + 1) * 512 + lane * 8];
            // swapped operands: C[row=k=kq*4+r][col=q=ml]
            f32x4 c = {0.f,0.f,0.f,0.f};
            c = __builtin_amdgcn_mfma_f32_16x16x32_bf16(bk0, aq0, c, 0, 0, 0);
            c = __builtin_amdgcn_mfma_f32_16x16x32_bf16(bk1, aq1, c, 0, 0, 0);
            float kna[4] = {kn4[jtl].x, kn4[jtl].y, kn4[jtl].z, kn4[jtl].w};
            float e[4], rb[4];
#pragma unroll
            for (int r = 0; r < 4; r++) {
                float qk = c[r];
                e[r] = __builtin_amdgcn_exp2f(qk * (0.125f * LOG2E));
                float tt = (2.f * qk - qn_l - kna[r]) * is2_l;
                rb[r] = fminf(__builtin_amdgcn_exp2f(tt), 1.0f);
                es_l += e[r]; rs_l += rb[r];
            }
            // pack 4 consecutive-k P values -> one b64 store per matrix
            uint2 pe = make_uint2(cvt_pk_bf16(e[0], e[1]), cvt_pk_bf16(e[2], e[3]));
            uint2 pr = make_uint2(cvt_pk_bf16(rb[0], rb[1]), cvt_pk_bf16(rb[2], rb[3]));
            *(uint2*)&PeW[ml * 72 + jtl * 16 + kq * 4] = pe;
            *(uint2*)&PrW[ml * 72 + jtl * 16 + kq * 4] = pr;
        }
        // (no barrier: P round-trip is wave-local)

#pragma unroll
        for (int jcl = 0; jcl < 2; jcl++) {
            bf16x8 pa_e = *(const bf16x8*)&PeW[ml * 72 + jcl * 32 + kq * 8];
            bf16x8 pa_r = *(const bf16x8*)&PrW[ml * 72 + jcl * 32 + kq * 8];
#pragma unroll
            for (int dt = 0; dt < 4; dt++) {
                bf16x8 bv = *(const bf16x8*)&VtW[(jcl * 4 + dt) * 512 + lane * 8];
                Oe[dt] = __builtin_amdgcn_mfma_f32_16x16x32_bf16(pa_e, bv, Oe[dt], 0, 0, 0);
                Or[dt] = __builtin_amdgcn_mfma_f32_16x16x32_bf16(pa_r, bv, Or[dt], 0, 0, 0);
            }
        }
        __builtin_amdgcn_s_setprio(0);
    }

    // es/rs: sum the 4 kq copies of each q=ml row
    es_l += __shfl_xor(es_l, 16);
    es_l += __shfl_xor(es_l, 32);
    rs_l += __shfl_xor(rs_l, 16);
    rs_l += __shfl_xor(rs_l, 32);

    // cross-half combine in LDS (Kt region is dead after the loop)
    __syncthreads();                     // everyone past the last QK read of Kt
    float* cb = (float*)Kt;              // 16 KB: [wq*64+lane][32]
    if (wp == 1) {
        float* cl = cb + (size_t)(wq * 64 + lane) * 32;
#pragma unroll
        for (int dt = 0; dt < 4; dt++)
#pragma unroll
            for (int r = 0; r < 4; r++) {
                cl[dt * 4 + r] = Oe[dt][r];
                cl[16 + dt * 4 + r] = Or[dt][r];
            }
        if (kq == 0) {
            esx[wq][ml] = es_l;
            rsx[wq][ml] = rs_l;
        }
    }
    __syncthreads();
    if (wp == 0) {
        float p = pond[0];
        float sv = 1.0f / (1.0f + __expf(-p));
        float p0 = 1.0f - sv, p1 = sv;
        float blendinv = 1.0f / (p0 + p1 + 1e-7f);
        // per-lane totals for q = ml, then redistribute to q = kq*4+r
        float es_q = es_l + esx[wq][ml];
        float rs_q = rs_l + rsx[wq][ml];
        const float* cl = cb + (size_t)(wq * 64 + lane) * 32;
        float we[4], wr[4];
#pragma unroll
        for (int r = 0; r < 4; r++) {
            float es = __shfl(es_q, kq * 4 + r);
            float rs = __shfl(rs_q, kq * 4 + r);
            we[r] = p0 * blendinv / es;
            wr[r] = p1 * blendinv / fmaxf(rs, 1e-8f);
        }
#pragma unroll
        for (int dt = 0; dt < 4; dt++) {
#pragma unroll
            for (int r = 0; r < 4; r++) {
                float oe = Oe[dt][r] + cl[dt * 4 + r];
                float orr = Or[dt][r] + cl[16 + dt * 4 + r];
                float v = oe * we[r] + orr * wr[r];
                int token = b * S_LEN + qt2 * 32 + wq * 16 + kq * 4 + r;
                vals[(size_t)token * 768 + h * 64 + dt * 16 + ml] = f2bf(v);
            }
        }
    }
}

// ---------------- launcher -------------------------------------------------

extern "C" void kernel_launch(void* const* d_in, const int* in_sizes, int n_in,
                              void* d_out, int out_size, void* d_ws, size_t ws_size,
                              hipStream_t stream) {
    const float* x     = (const float*)d_in[0];
    const float* ln1_w = (const float*)d_in[1];
    const float* ln1_b = (const float*)d_in[2];
    const float* Wq    = (const float*)d_in[3];
    const float* bq    = (const float*)d_in[4];
    const float* Wk    = (const float*)d_in[5];
    const float* bk    = (const float*)d_in[6];
    const float* Wv    = (const float*)d_in[7];
    const float* bv    = (const float*)d_in[8];
    const float* Wo    = (const float*)d_in[9];
    const float* bo    = (const float*)d_in[10];
    const float* pond  = (const float*)d_in[11];
    const float* ln2_w = (const float*)d_in[12];
    const float* ln2_b = (const float*)d_in[13];
    const float* fc1_W = (const float*)d_in[14];
    const float* fc1_b = (const float*)d_in[15];
    const float* vqc_W = (const float*)d_in[16];
    const float* vqc_b = (const float*)d_in[17];
    const float* fc2_W = (const float*)d_in[18];
    const float* fc2_b = (const float*)d_in[19];
    float* out = (float*)d_out;

    char* p = (char*)d_ws;
    short* Qb   = (short*)p;  p += (size_t)2048 * 768 * 2;
    short* Kfb  = (short*)p;  p += (size_t)2048 * 768 * 2;
    short* Vfb  = (short*)p;  p += (size_t)2048 * 768 * 2;
    float* x2   = (float*)p;  p += (size_t)2048 * 768 * 4;
    float* bqkv = (float*)p;  p += 2304 * 4;
    float* qnG  = (float*)p;  p += (size_t)24 * 1024 * 4;
    float* knG  = (float*)p;  p += (size_t)24 * 1024 * 4;
    short* actb = (short*)p;  p += (size_t)2048 * 768 * 2;
    short* g    = (short*)p;  p += (size_t)2048 * 3072 * 2;
    short* Avqc = (short*)p;  p += (size_t)8192 * 768 * 2;
    short* partb = (short*)p; p += (size_t)4 * 2048 * 768 * 2;   // 12.6 MB split-K partials
    short* wreg = (short*)p;  p += (size_t)5900544 * 2;
    short* Wqkvb = wreg;
    short* Wob   = wreg + 1769472;
    short* fc1b  = wreg + 2359296;
    short* vqcb  = wreg + 2951424;
    short* fc2b  = wreg + 3541248;

    dim3 blk(256);
    const size_t SP = (size_t)2048 * 768;

    // 0. preamble: ln1 + bias concat + QKV weight conversion only (3777 blocks)
    preamble<<<3777, blk, 0, stream>>>(Wq, Wk, Wv, Wo, fc1_W, vqc_W, fc2_W, wreg,
                                       bq, bk, bv, bqkv, x, ln1_w, ln1_b, actb);
    // 1. fused QKV projection (576 GEMM blocks) + qn/kn side outputs
    //    + 1026 appended converter blocks (y >= 32, dispatched last)
    gemm_bf16<3, 64><<<dim3(18, 89, 1), blk, 0, stream>>>(actb, 768, Wqkvb, 768, bqkv,
                                                          Qb, 768, 0, Kfb, Vfb, 2304, 768, 0,
                                                          qnG, knG,
                                                          Wo, fc1_W, vqc_W, fc2_W, wreg);
    // 2. MFMA attention (swapped-QK + setprio + exp2-fold), 768 blocks (3/CU)
    attn_mfma<<<768, blk, 0, stream>>>(Qb, Kfb, Vfb, pond, qnG, knG, actb);
    // 3. Wo split-K x4 (768 blocks = 3/CU)
    gemm_bf16<5, 64><<<dim3(6, 32, 4), blk, 0, stream>>>(actb, 768, Wob, 768, nullptr,
                                                         partb, 768, SP,
                                                         nullptr, nullptr, 768, 192, 0,
                                                         nullptr, nullptr,
                                                         nullptr, nullptr, nullptr, nullptr, nullptr);
    // 4. reduce + bo + residual(x) -> x2 fp32, fused ln2 -> actb
    reduce_wo_ln<<<2048, blk, 0, stream>>>(partb, bo, x, ln2_w, ln2_b, x2, actb);
    // 5. fc1 split-K x4, cols 0..767 only (768 blocks = 3/CU exact)
    gemm_bf16<5, 64><<<dim3(6, 32, 4), blk, 0, stream>>>(actb, 768, fc1b, 768, nullptr,
                                                         partb, 768, SP,
                                                         nullptr, nullptr, 768, 192, 0,
                                                         nullptr, nullptr,
                                                         nullptr, nullptr, nullptr, nullptr, nullptr);
    // 6. reduce + bias + cols 768..770 dots + expand -> Avqc [8192][768]
    reduce_fc1_expand<<<2048, blk, 0, stream>>>(partb, fc1_b, actb, fc1b + 768 * 768, Avqc);
    // 7. vqc (direct) + bias + gelu + transpose scatter (768 blocks = 3/CU)
    gemm_bf16<2, 64><<<dim3(6, 128, 1), blk, 0, stream>>>(Avqc, 768, vqcb, 768, vqc_b,
                                                          g, 3072, 0, nullptr, nullptr, 768, 768, 1,
                                                          nullptr, nullptr,
                                                          nullptr, nullptr, nullptr, nullptr, nullptr);
    // 8. fc2 split-K x4 (768 blocks = 3/CU)
    gemm_bf16<5, 64><<<dim3(6, 32, 4), blk, 0, stream>>>(g, 3072, fc2b, 3072, nullptr,
                                                         partb, 768, SP,
                                                         nullptr, nullptr, 768, 768, 0,
                                                         nullptr, nullptr,
                                                         nullptr, nullptr, nullptr, nullptr, nullptr);
    // 9. reduce + bias + residual(x2) -> out fp32
    reduce_fc2<<<1536, blk, 0, stream>>>(partb, fc2_b, x2, out);
}

// Round 13
// 142.819 us; speedup vs baseline: 1.0311x; 1.0159x over previous
//
#include <hip/hip_runtime.h>
#include <math.h>

#define E_DIM 768
#define S_LEN 1024
#define B_SZ 2
#define H_CNT 12
#define D_HEAD 64
#define M_DIM 768
#define Q_STRIDE 4
#define N_FC1 771            // only M+Q-1 columns of fc1 are consumed

typedef __attribute__((ext_vector_type(8))) short bf16x8;
typedef __attribute__((ext_vector_type(4))) float f32x4;

#define AS1 __attribute__((address_space(1)))
#define AS3 __attribute__((address_space(3)))

__device__ __forceinline__ void gld_lds16(void* lds, const void* g) {
    __builtin_amdgcn_global_load_lds((const AS1 void*)g, (AS3 void*)lds, 16, 0, 0);
}

__device__ __forceinline__ short f2bf(float f) {
    unsigned u = __float_as_uint(f);
    unsigned r = (u + 0x7fffu + ((u >> 16) & 1u)) >> 16;
    return (short)r;
}

__device__ __forceinline__ float bf2f(short s) {
    return __uint_as_float(((unsigned)(unsigned short)s) << 16);
}

// pack two f32 -> one dword of 2 bf16 (RNE), single instruction
__device__ __forceinline__ unsigned cvt_pk_bf16(float lo, float hi) {
    unsigned r;
    asm("v_cvt_pk_bf16_f32 %0, %1, %2" : "=v"(r) : "v"(lo), "v"(hi));
    return r;
}

// ---------------- block reduction helpers (256 threads, 4 waves) -----------

__device__ __forceinline__ float block_reduce_sum(float v, volatile float* red) {
#pragma unroll
    for (int off = 32; off > 0; off >>= 1) v += __shfl_xor(v, off);
    __syncthreads();
    if ((threadIdx.x & 63) == 0) red[threadIdx.x >> 6] = v;
    __syncthreads();
    return red[0] + red[1] + red[2] + red[3];
}

// R23: joint (sum, sumsq) reduction -- one barrier pair instead of two
// sequential block_reduce_sum calls (4 barriers + dependent second pass).
__device__ __forceinline__ void block_reduce_sum2(float a, float b,
                                                  volatile float* red2,
                                                  float* oa, float* ob) {
#pragma unroll
    for (int off = 32; off > 0; off >>= 1) {
        a += __shfl_xor(a, off);
        b += __shfl_xor(b, off);
    }
    __syncthreads();
    if ((threadIdx.x & 63) == 0) {
        int wv = threadIdx.x >> 6;
        red2[wv * 2]     = a;
        red2[wv * 2 + 1] = b;
    }
    __syncthreads();
    *oa = red2[0] + red2[2] + red2[4] + red2[6];
    *ob = red2[1] + red2[3] + red2[5] + red2[7];
}

// ------------- preamble: ln1 + bias concat + QKV weight conversion --------
// R20: preamble converts ONLY the QKV weights; Wo/fc1/vqc/fc2 conversion is
// backfilled into the QKV GEMM dispatch (see gemm_bf16 OUTMODE==3).
// R23: single-pass LN via joint (sum,sumsq) reduce; var = E[x^2] - mu^2.

__global__ __launch_bounds__(256) void preamble(
        const float* __restrict__ Wq, const float* __restrict__ Wk,
        const float* __restrict__ Wv, const float* __restrict__ Wo,
        const float* __restrict__ fc1W, const float* __restrict__ vqcW,
        const float* __restrict__ fc2W, short* __restrict__ dst,
        const float* __restrict__ bq, const float* __restrict__ bk,
        const float* __restrict__ bv, float* __restrict__ bqkv,
        const float* __restrict__ x, const float* __restrict__ ln1_w,
        const float* __restrict__ ln1_b, short* __restrict__ actb) {
    __shared__ float red2[8];
    int tid = threadIdx.x;
    if (blockIdx.x < 2048) {          // ln1 (single-pass)
        int row = blockIdx.x;
        const float* xr = x + (size_t)row * E_DIM;
        float v0 = xr[tid], v1 = xr[tid + 256], v2 = xr[tid + 512];
        float s, s2;
        block_reduce_sum2(v0 + v1 + v2, v0 * v0 + v1 * v1 + v2 * v2, red2, &s, &s2);
        float mu = s * (1.0f / E_DIM);
        float var = s2 * (1.0f / E_DIM) - mu * mu;
        float rs = rsqrtf(var + 1e-5f);
        short* orow = actb + (size_t)row * E_DIM;
        orow[tid]       = f2bf((v0 - mu) * rs * ln1_w[tid]       + ln1_b[tid]);
        orow[tid + 256] = f2bf((v1 - mu) * rs * ln1_w[tid + 256] + ln1_b[tid + 256]);
        orow[tid + 512] = f2bf((v2 - mu) * rs * ln1_w[tid + 512] + ln1_b[tid + 512]);
        return;
    }
    if (blockIdx.x == 2048) {         // bias concat
#pragma unroll
        for (int u = 0; u < 9; u++) {
            int i = tid + u * 256;
            float v = (i < 768) ? bq[i] : (i < 1536) ? bk[i - 768] : bv[i - 1536];
            bqkv[i] = v;
        }
        return;
    }
    int t = (blockIdx.x - 2049) * 256 + tid;      // float4 index
    if (t >= 442368) return;                      // QKV weights only: 1769472 / 4
    int e = t * 4;
    const float* src; int off;
    if      (e < 589824)  { src = Wq;   off = e; }
    else if (e < 1179648) { src = Wk;   off = e - 589824; }
    else                  { src = Wv;   off = e - 1179648; }
    float4 v = *(const float4*)(src + off);
    short4 o = make_short4(f2bf(v.x), f2bf(v.y), f2bf(v.z), f2bf(v.w));
    *(short4*)(dst + e) = o;
}

// ---------------- bf16 MFMA NT GEMM (BK=64, double-buffered, MR-templated) -
// MR x 128 tile, BK=64 (two MRx32 sub-slabs), double-buffered (one barrier
// per iteration). LDS 48 KB at MR=64 -> 3 blocks/CU, matching 768-block
// balanced grids (R10). R18/R7 lesson: MR=128 shrinks grids to 288-384
// blocks = 1.1-1.5/CU -> grid imbalance costs more than the tile wins.
// OUTMODE: 2 = bias+GELU+bf16 transpose-scatter (vqc); 3 = QKV split
//          (+ fp32 q/k row-norm side outputs qnG/knG; + R20 appended
//          weight-converter blocks at blockIdx.y >= 32); 5 = bf16 partial.

template <int OUTMODE, int MR>
__global__ __launch_bounds__(256, 2) void gemm_bf16(
        const short* __restrict__ A, int lda,
        const short* __restrict__ W, int ldw,
        const float* __restrict__ bias,
        void* __restrict__ outp, int ldo, size_t spitch,
        short* __restrict__ Kfp, short* __restrict__ Vfp,
        int N, int klen, int dogelu,
        float* __restrict__ qnG, float* __restrict__ knG,
        const float* __restrict__ cW0, const float* __restrict__ cW1,
        const float* __restrict__ cW2, const float* __restrict__ cW3,
        short* __restrict__ cdst) {
    if constexpr (OUTMODE == 3) {
        // appended weight-converter blocks (dispatched last: y >= 32)
        if (blockIdx.y >= 32) {
            int cid = (blockIdx.y - 32) * 18 + blockIdx.x;
            int tid = threadIdx.x;
#pragma unroll
            for (int u = 0; u < 4; u++) {
                int t = cid * 1024 + u * 256 + tid;   // float4 idx in remaining region
                if (t < 1032768) {
                    int e = 1769472 + t * 4;          // global float idx
                    const float* src; int off;
                    if      (e < 2359296) { src = cW0; off = e - 1769472; }  // Wo
                    else if (e < 2951424) { src = cW1; off = e - 2359296; }  // fc1
                    else if (e < 3541248) { src = cW2; off = e - 2951424; }  // vqc
                    else                  { src = cW3; off = e - 3541248; }  // fc2
                    float4 v = *(const float4*)(src + off);
                    short4 o = make_short4(f2bf(v.x), f2bf(v.y), f2bf(v.z), f2bf(v.w));
                    *(short4*)(cdst + e) = o;
                }
            }
            return;
        }
    }
    constexpr int MI = MR / 32;
    constexpr int AH = MR * 32;
    constexpr int NA = MR / 64;
    constexpr int ASL = 2 * AH;
    __shared__ short At[2 * ASL];
    __shared__ short Bt[2 * 8192];
    const int tid = threadIdx.x;
    const int lane = tid & 63;
    const int wave = tid >> 6;
    const int wr = (wave >> 1) * (MI * 16);
    const int wc = (wave & 1) * 64;
    const int ml = lane & 15;
    const int kq = lane >> 4;
    const int row0 = blockIdx.y * MR;
    const int col0 = blockIdx.x * 128;
    const int kbase = blockIdx.z * klen;

    const short* Ag[NA]; int aoff[NA];
#pragma unroll
    for (int u = 0; u < NA; u++) {
        int c = tid + u * 256;
        int am = c >> 2, ak = ((c & 3) ^ ((am >> 1) & 3)) * 8;
        Ag[u] = A + (size_t)(row0 + am) * lda + ak + kbase;
        aoff[u] = c * 8;
    }
    const int c0 = tid, c1 = tid + 256;
    const int bm0 = c0 >> 2, bk0 = (((c0 & 3) ^ ((bm0 >> 1) & 3))) * 8;
    const int bm1 = c1 >> 2, bk1 = (((c1 & 3) ^ ((bm1 >> 1) & 3))) * 8;
    int wrow0 = col0 + bm0; if (wrow0 > N - 1) wrow0 = N - 1;
    int wrow1 = col0 + bm1; if (wrow1 > N - 1) wrow1 = N - 1;
    const short* Wg0 = W + (size_t)wrow0 * ldw + bk0 + kbase;
    const short* Wg1 = W + (size_t)wrow1 * ldw + bk1 + kbase;

    const int kxor = (kq ^ ((ml >> 1) & 3)) * 8;

    f32x4 acc[MI][4];
#pragma unroll
    for (int i = 0; i < MI; i++)
#pragma unroll
        for (int j = 0; j < 4; j++) acc[i][j] = {0.f, 0.f, 0.f, 0.f};

    auto stage = [&](int buf, int k0) {
        short* Ab = At + buf * ASL;
        short* Bb = Bt + buf * 8192;
#pragma unroll
        for (int u = 0; u < NA; u++) {
            gld_lds16(Ab + aoff[u], Ag[u] + k0);
            gld_lds16(Ab + AH + aoff[u], Ag[u] + k0 + 32);
        }
        gld_lds16(Bb + c0 * 8, Wg0 + k0);
        gld_lds16(Bb + c1 * 8, Wg1 + k0);
        gld_lds16(Bb + 4096 + c0 * 8, Wg0 + k0 + 32);
        gld_lds16(Bb + 4096 + c1 * 8, Wg1 + k0 + 32);
    };

    stage(0, 0);
    int cur = 0;
    for (int k0 = 0; k0 < klen; k0 += 64) {
        __syncthreads();
        if (k0 + 64 < klen) stage(cur ^ 1, k0 + 64);
        const short* Ac = At + cur * ASL;
        const short* Bc = Bt + cur * 8192;
#pragma unroll
        for (int half = 0; half < 2; half++) {
            const short* Ah = Ac + half * AH;
            const short* Bh = Bc + half * 4096;
            bf16x8 af[MI], bfr[4];
#pragma unroll
            for (int i = 0; i < MI; i++)
                af[i] = *(const bf16x8*)&Ah[(wr + i * 16 + ml) * 32 + kxor];
#pragma unroll
            for (int j = 0; j < 4; j++)
                bfr[j] = *(const bf16x8*)&Bh[(wc + j * 16 + ml) * 32 + kxor];
#pragma unroll
            for (int i = 0; i < MI; i++)
#pragma unroll
                for (int j = 0; j < 4; j++)
                    acc[i][j] = __builtin_amdgcn_mfma_f32_16x16x32_bf16(af[i], bfr[j], acc[i][j], 0, 0, 0);
        }
        cur ^= 1;
    }

    // epilogue: C/D layout col = lane&15, row = (lane>>4)*4 + reg
    float sq[MI][4];
    if constexpr (OUTMODE == 3) {
#pragma unroll
        for (int i = 0; i < MI; i++)
#pragma unroll
            for (int rr = 0; rr < 4; rr++) sq[i][rr] = 0.f;
    }
#pragma unroll
    for (int i = 0; i < MI; i++) {
#pragma unroll
        for (int j = 0; j < 4; j++) {
#pragma unroll
            for (int rr = 0; rr < 4; rr++) {
                int r = row0 + wr + i * 16 + kq * 4 + rr;
                int c = col0 + wc + j * 16 + ml;
                if (c < N) {
                    float v = acc[i][j][rr];
                    if (OUTMODE < 4) v += bias[c];
                    if (OUTMODE == 2 && dogelu)
                        v = 0.5f * v * (1.0f + erff(v * 0.70710678118654752f));
                    if (OUTMODE == 2) {
                        ((short*)outp)[(size_t)(r >> 2) * ldo + c * 4 + (r & 3)] = f2bf(v);
                    } else if (OUTMODE == 5) {
                        ((short*)outp)[blockIdx.z * spitch + (size_t)r * ldo + c] = f2bf(v);
                    } else if (OUTMODE == 3) {
                        sq[i][rr] += v * v;
                        int s = r & 1023, bb = r >> 10;
                        if (c < 768) {
                            ((short*)outp)[(size_t)r * 768 + c] = f2bf(v);
                        } else if (c < 1536) {
                            int df = c - 768; int hh = df >> 6, d = df & 63;
                            int bh2 = bb * 12 + hh;
                            size_t idx = ((size_t)(bh2 * 64 + (s >> 4)) * 2 + (d >> 5)) * 512
                                       + (size_t)((d >> 3) & 3) * 128 + (size_t)(s & 15) * 8 + (d & 7);
                            Kfp[idx] = f2bf(v);
                        } else {
                            int df = c - 1536; int hh = df >> 6, d = df & 63;
                            int bh2 = bb * 12 + hh;
                            size_t idx = ((size_t)(bh2 * 32 + (s >> 5))) * 2048
                                       + (size_t)(d >> 4) * 512 + (size_t)((s >> 3) & 3) * 128
                                       + (size_t)(d & 15) * 8 + (s & 7);
                            Vfp[idx] = f2bf(v);
                        }
                    }
                }
            }
        }
    }

    if constexpr (OUTMODE == 3) {
        // fp32 row-norm side outputs. Each wave's 64-col span [cb, cb+64)
        // is exactly one (matrix, head) group (col0, wc multiples of 64).
        int cb = col0 + wc;
        if (cb < 1536) {
            float* dst = (cb < 768) ? qnG : knG;
            int hh = ((cb < 768) ? cb : cb - 768) >> 6;
#pragma unroll
            for (int i = 0; i < MI; i++) {
#pragma unroll
                for (int rr = 0; rr < 4; rr++) {
                    float s = sq[i][rr];
                    s += __shfl_xor(s, 1);
                    s += __shfl_xor(s, 2);
                    s += __shfl_xor(s, 4);
                    s += __shfl_xor(s, 8);
                    if (ml == 0) {
                        int r = row0 + wr + i * 16 + kq * 4 + rr;
                        int bb = r >> 10, sidx = r & 1023;
                        dst[(size_t)(bb * 12 + hh) * 1024 + sidx] = s;
                    }
                }
            }
        }
    }
}

// ---------------- split-K reduce kernels -----------------------------------

// Wo partials (4, bf16) + bo + residual x -> x2 fp32, then LN(ln2) -> y bf16
// R23: single-pass LN (joint sum/sumsq reduce, var = E[x^2]-mu^2).
__global__ __launch_bounds__(256) void reduce_wo_ln(
        const short* __restrict__ part, const float* __restrict__ bo,
        const float* __restrict__ x, const float* __restrict__ w,
        const float* __restrict__ bvec, float* __restrict__ x2,
        short* __restrict__ y) {
    __shared__ float red2[8];
    int row = blockIdx.x, tid = threadIdx.x;
    const size_t SP = (size_t)2048 * 768;
    const short* pr = part + (size_t)row * 768;
    const float* xr = x + (size_t)row * 768;
    float* x2r = x2 + (size_t)row * 768;
    float v[3];
#pragma unroll
    for (int u = 0; u < 3; u++) {
        int c = tid + u * 256;
        float s = bo[c] + xr[c];
#pragma unroll
        for (int z = 0; z < 4; z++) s += bf2f(pr[z * SP + c]);
        v[u] = s; x2r[c] = s;
    }
    float s, s2;
    block_reduce_sum2(v[0] + v[1] + v[2],
                      v[0] * v[0] + v[1] * v[1] + v[2] * v[2], red2, &s, &s2);
    float mu = s * (1.0f / 768.f);
    float var = s2 * (1.0f / 768.f) - mu * mu;
    float rs = rsqrtf(var + 1e-5f);
    short* orow = y + (size_t)row * 768;
    orow[tid]       = f2bf((v[0] - mu) * rs * w[tid]       + bvec[tid]);
    orow[tid + 256] = f2bf((v[1] - mu) * rs * w[tid + 256] + bvec[tid + 256]);
    orow[tid + 512] = f2bf((v[2] - mu) * rs * w[tid + 512] + bvec[tid + 512]);
}

// fc1 partials (4, bf16 [2048][768], cols 0..767) + bias -> expanded slices.
// Cols 768..770 computed here as block-reduced dots y[r].fc1_W[768+k] so the
// fc1 GEMM runs an exact 768-block grid. Avqc[(r*4+q)][m] = h1[r][m+q].
// R23: the 3 dots are reduced JOINTLY (one barrier pair, per-wave slots)
// instead of 3 sequential block_reduce_sum (7 barriers -> 2).
__global__ __launch_bounds__(256) void reduce_fc1_expand(
        const short* __restrict__ part, const float* __restrict__ b,
        const short* __restrict__ y, const short* __restrict__ w768,
        short* __restrict__ Avqc) {
    __shared__ float row[772];
    __shared__ float red3[4][3];
    int r = blockIdx.x, tid = threadIdx.x;
    const size_t SP = (size_t)2048 * 768;
    const short* pr = part + (size_t)r * 768;
#pragma unroll
    for (int u = 0; u < 3; u++) {
        int c = tid + u * 256;
        float s = b[c];
#pragma unroll
        for (int z = 0; z < 4; z++) s += bf2f(pr[z * SP + c]);
        row[c] = s;
    }
    const short* yr = y + (size_t)r * 768;
    float y0 = bf2f(yr[tid]), y1 = bf2f(yr[tid + 256]), y2 = bf2f(yr[tid + 512]);
    float p[3];
#pragma unroll
    for (int k = 0; k < 3; k++) {
        const short* wk = w768 + k * 768;
        p[k] = y0 * bf2f(wk[tid]) + y1 * bf2f(wk[tid + 256]) + y2 * bf2f(wk[tid + 512]);
    }
#pragma unroll
    for (int off = 32; off > 0; off >>= 1) {
        p[0] += __shfl_xor(p[0], off);
        p[1] += __shfl_xor(p[1], off);
        p[2] += __shfl_xor(p[2], off);
    }
    __syncthreads();                 // also covers row[c] writes above
    if ((tid & 63) == 0) {
        int wv = tid >> 6;
        red3[wv][0] = p[0]; red3[wv][1] = p[1]; red3[wv][2] = p[2];
    }
    __syncthreads();
    if (tid < 3) {
        row[768 + tid] = red3[0][tid] + red3[1][tid] + red3[2][tid] + red3[3][tid]
                       + b[768 + tid];
    }
    __syncthreads();
#pragma unroll
    for (int q = 0; q < 4; q++) {
        short* orow = Avqc + (size_t)(r * 4 + q) * 768;
#pragma unroll
        for (int u = 0; u < 3; u++) {
            int m = tid + u * 256;
            orow[m] = f2bf(row[m + q]);
        }
    }
}

// fc2 partials (4, bf16) + bias + residual x2 -> out fp32
__global__ __launch_bounds__(256) void reduce_fc2(
        const short* __restrict__ part, const float* __restrict__ b,
        const float* __restrict__ x2, float* __restrict__ out) {
    int t = blockIdx.x * 256 + threadIdx.x;
    int row = t / 192;
    int c = (t - row * 192) * 4;
    size_t off = (size_t)row * 768 + c;
    const size_t SP = (size_t)2048 * 768;
    float4 bb = *(const float4*)(b + c);
    float4 xx = *(const float4*)(x2 + off);
    float o0 = bb.x + xx.x, o1 = bb.y + xx.y, o2 = bb.z + xx.z, o3 = bb.w + xx.w;
#pragma unroll
    for (int z = 0; z < 4; z++) {
        short4 v = *(const short4*)(part + z * SP + off);
        o0 += bf2f(v.x); o1 += bf2f(v.y); o2 += bf2f(v.z); o3 += bf2f(v.w);
    }
    float4 o = make_float4(o0, o1, o2, o3);
    *(float4*)(out + off) = o;
}

// ---------------- MFMA fused attention, INTRA-BLOCK KV-split ---------------
// R22 (banked): T5 s_setprio(1) around compute phase; exp->exp2 with log2e
// folded into the softmax scale and is_l. R19: swapped-operand QK
// (mfma(bk,aq) -> C[k][q]), cvt_pk P-pack, one b64 store per jtl. Base =
// R4 measured-best (staged K/V, norm tables, XCD swizzle).

#define LOG2E 1.44269504088896340736f

__global__ __launch_bounds__(256) void attn_mfma(
        const short* __restrict__ Qb,    // [2048][768] bf16
        const short* __restrict__ Kf,    // frag-major
        const short* __restrict__ Vf,    // frag-major
        const float* __restrict__ pond,
        const float* __restrict__ qnG,   // [24][1024] fp32 |q|^2
        const float* __restrict__ knG,   // [24][1024] fp32 |k|^2
        short* __restrict__ vals) {      // [2048][768] bf16
    __shared__ __align__(16) short Kt[2 * 4096];   // [wp][tile]; reused as combine buf
    __shared__ __align__(16) short Vt[2 * 4096];
    __shared__ float esx[2][16], rsx[2][16];
    __shared__ __align__(16) short Pe[4 * 16 * 72];
    __shared__ __align__(16) short Pr[4 * 16 * 72];

    const int tid = threadIdx.x;
    const int lane = tid & 63;
    const int wave = tid >> 6;
    const int wq = wave & 1;       // q sub-tile
    const int wp = wave >> 1;      // KV half
    const int ml = lane & 15;
    const int kq = lane >> 4;

    // XCD-affinity swizzle (768 = 8 XCDs x 96 -> bijective)
    const int fid = blockIdx.x;
    const int w = (fid & 7) * 96 + (fid >> 3);
    const int qt2 = w & 31;
    const int bh = w >> 5;          // 0..23
    const int b = (bh >= 12) ? 1 : 0;
    const int h = bh - b * 12;

    const int qrow = b * S_LEN + qt2 * 32 + wq * 16 + ml;
    const short* qp = Qb + (size_t)qrow * 768 + h * 64 + kq * 8;
    bf16x8 aq0 = *(const bf16x8*)qp;
    bf16x8 aq1 = *(const bf16x8*)(qp + 32);

    // scalar q-norm for this lane's q-row (q = ml); log2e folded into is2
    const float* qnB = qnG + (size_t)bh * 1024 + qt2 * 32 + wq * 16;
    float qn_l = qnB[ml];
    float is2_l = LOG2E / fminf(fmaxf(qn_l, 1e-8f), 1e4f);
    const float* knB = knG + (size_t)bh * 1024;

    f32x4 Oe[4], Or[4];
#pragma unroll
    for (int dt = 0; dt < 4; dt++) { Oe[dt] = {0.f,0.f,0.f,0.f}; Or[dt] = {0.f,0.f,0.f,0.f}; }
    float es_l = 0.f, rs_l = 0.f;

    const short* KfB = Kf + (size_t)bh * 65536;
    const short* VfB = Vf + (size_t)bh * 65536;
    short* PeW = Pe + wave * 1152;
    short* PrW = Pr + wave * 1152;
    const short* KtW = Kt + wp * 4096;
    const short* VtW = Vt + wp * 4096;

    for (int it = 0; it < 8; it++) {
        __syncthreads();   // all waves done reading prior tiles
        {
            const short* sk0 = KfB + it * 4096 + tid * 8;
            gld_lds16(Kt + tid * 8, sk0);
            gld_lds16(Kt + 2048 + tid * 8, sk0 + 2048);
            const short* sk1 = KfB + (it + 8) * 4096 + tid * 8;
            gld_lds16(Kt + 4096 + tid * 8, sk1);
            gld_lds16(Kt + 6144 + tid * 8, sk1 + 2048);
            const short* sv0 = VfB + it * 4096 + tid * 8;
            gld_lds16(Vt + tid * 8, sv0);
            gld_lds16(Vt + 2048 + tid * 8, sv0 + 2048);
            const short* sv1 = VfB + (it + 8) * 4096 + tid * 8;
            gld_lds16(Vt + 4096 + tid * 8, sv1);
            gld_lds16(Vt + 6144 + tid * 8, sv1 + 2048);
        }
        // k-norms for this wave's tile (4 consecutive per lane per jtl);
        // loads land under the barrier's vmcnt drain
        float4 kn4[4];
        {
            const float* knI = knB + (it + 8 * wp) * 64;
#pragma unroll
            for (int jtl = 0; jtl < 4; jtl++)
                kn4[jtl] = *(const float4*)(knI + jtl * 16 + kq * 4);
        }
        __syncthreads();   // tiles resident

        __builtin_amdgcn_s_setprio(1);
#pragma unroll
        for (int jtl = 0; jtl < 4; jtl++) {
            bf16x8 bk0 = *(const bf16x8*)&KtW[(jtl * 2 + 0) * 512 + lane * 8];
            bf16x8 bk1 = *(const bf16x8*)&KtW[(jtl * 2 + 1) * 512 + lane * 8];
            // swapped operands: C[row=k=kq*4+r][col=q=ml]
            f32x4 c = {0.f,0.f,0.f,0.f};
            c = __builtin_amdgcn_mfma_f32_16x16x32_bf16(bk0, aq0, c, 0, 0, 0);
            c = __builtin_amdgcn_mfma_f32_16x16x32_bf16(bk1, aq1, c, 0, 0, 0);
            float kna[4] = {kn4[jtl].x, kn4[jtl].y, kn4[jtl].z, kn4[jtl].w};
            float e[4], rb[4];
#pragma unroll
            for (int r = 0; r < 4; r++) {
                float qk = c[r];
                e[r] = __builtin_amdgcn_exp2f(qk * (0.125f * LOG2E));
                float tt = (2.f * qk - qn_l - kna[r]) * is2_l;
                rb[r] = fminf(__builtin_amdgcn_exp2f(tt), 1.0f);
                es_l += e[r]; rs_l += rb[r];
            }
            // pack 4 consecutive-k P values -> one b64 store per matrix
            uint2 pe = make_uint2(cvt_pk_bf16(e[0], e[1]), cvt_pk_bf16(e[2], e[3]));
            uint2 pr = make_uint2(cvt_pk_bf16(rb[0], rb[1]), cvt_pk_bf16(rb[2], rb[3]));
            *(uint2*)&PeW[ml * 72 + jtl * 16 + kq * 4] = pe;
            *(uint2*)&PrW[ml * 72 + jtl * 16 + kq * 4] = pr;
        }
        // (no barrier: P round-trip is wave-local)

#pragma unroll
        for (int jcl = 0; jcl < 2; jcl++) {
            bf16x8 pa_e = *(const bf16x8*)&PeW[ml * 72 + jcl * 32 + kq * 8];
            bf16x8 pa_r = *(const bf16x8*)&PrW[ml * 72 + jcl * 32 + kq * 8];
#pragma unroll
            for (int dt = 0; dt < 4; dt++) {
                bf16x8 bv = *(const bf16x8*)&VtW[(jcl * 4 + dt) * 512 + lane * 8];
                Oe[dt] = __builtin_amdgcn_mfma_f32_16x16x32_bf16(pa_e, bv, Oe[dt], 0, 0, 0);
                Or[dt] = __builtin_amdgcn_mfma_f32_16x16x32_bf16(pa_r, bv, Or[dt], 0, 0, 0);
            }
        }
        __builtin_amdgcn_s_setprio(0);
    }

    // es/rs: sum the 4 kq copies of each q=ml row
    es_l += __shfl_xor(es_l, 16);
    es_l += __shfl_xor(es_l, 32);
    rs_l += __shfl_xor(rs_l, 16);
    rs_l += __shfl_xor(rs_l, 32);

    // cross-half combine in LDS (Kt region is dead after the loop)
    __syncthreads();                     // everyone past the last QK read of Kt
    float* cb = (float*)Kt;              // 16 KB: [wq*64+lane][32]
    if (wp == 1) {
        float* cl = cb + (size_t)(wq * 64 + lane) * 32;
#pragma unroll
        for (int dt = 0; dt < 4; dt++)
#pragma unroll
            for (int r = 0; r < 4; r++) {
                cl[dt * 4 + r] = Oe[dt][r];
                cl[16 + dt * 4 + r] = Or[dt][r];
            }
        if (kq == 0) {
            esx[wq][ml] = es_l;
            rsx[wq][ml] = rs_l;
        }
    }
    __syncthreads();
    if (wp == 0) {
        float p = pond[0];
        float sv = 1.0f / (1.0f + __expf(-p));
        float p0 = 1.0f - sv, p1 = sv;
        float blendinv = 1.0f / (p0 + p1 + 1e-7f);
        // per-lane totals for q = ml, then redistribute to q = kq*4+r
        float es_q = es_l + esx[wq][ml];
        float rs_q = rs_l + rsx[wq][ml];
        const float* cl = cb + (size_t)(wq * 64 + lane) * 32;
        float we[4], wr[4];
#pragma unroll
        for (int r = 0; r < 4; r++) {
            float es = __shfl(es_q, kq * 4 + r);
            float rs = __shfl(rs_q, kq * 4 + r);
            we[r] = p0 * blendinv / es;
            wr[r] = p1 * blendinv / fmaxf(rs, 1e-8f);
        }
#pragma unroll
        for (int dt = 0; dt < 4; dt++) {
#pragma unroll
            for (int r = 0; r < 4; r++) {
                float oe = Oe[dt][r] + cl[dt * 4 + r];
                float orr = Or[dt][r] + cl[16 + dt * 4 + r];
                float v = oe * we[r] + orr * wr[r];
                int token = b * S_LEN + qt2 * 32 + wq * 16 + kq * 4 + r;
                vals[(size_t)token * 768 + h * 64 + dt * 16 + ml] = f2bf(v);
            }
        }
    }
}

// ---------------- launcher -------------------------------------------------

extern "C" void kernel_launch(void* const* d_in, const int* in_sizes, int n_in,
                              void* d_out, int out_size, void* d_ws, size_t ws_size,
                              hipStream_t stream) {
    const float* x     = (const float*)d_in[0];
    const float* ln1_w = (const float*)d_in[1];
    const float* ln1_b = (const float*)d_in[2];
    const float* Wq    = (const float*)d_in[3];
    const float* bq    = (const float*)d_in[4];
    const float* Wk    = (const float*)d_in[5];
    const float* bk    = (const float*)d_in[6];
    const float* Wv    = (const float*)d_in[7];
    const float* bv    = (const float*)d_in[8];
    const float* Wo    = (const float*)d_in[9];
    const float* bo    = (const float*)d_in[10];
    const float* pond  = (const float*)d_in[11];
    const float* ln2_w = (const float*)d_in[12];
    const float* ln2_b = (const float*)d_in[13];
    const float* fc1_W = (const float*)d_in[14];
    const float* fc1_b = (const float*)d_in[15];
    const float* vqc_W = (const float*)d_in[16];
    const float* vqc_b = (const float*)d_in[17];
    const float* fc2_W = (const float*)d_in[18];
    const float* fc2_b = (const float*)d_in[19];
    float* out = (float*)d_out;

    char* p = (char*)d_ws;
    short* Qb   = (short*)p;  p += (size_t)2048 * 768 * 2;
    short* Kfb  = (short*)p;  p += (size_t)2048 * 768 * 2;
    short* Vfb  = (short*)p;  p += (size_t)2048 * 768 * 2;
    float* x2   = (float*)p;  p += (size_t)2048 * 768 * 4;
    float* bqkv = (float*)p;  p += 2304 * 4;
    float* qnG  = (float*)p;  p += (size_t)24 * 1024 * 4;
    float* knG  = (float*)p;  p += (size_t)24 * 1024 * 4;
    short* actb = (short*)p;  p += (size_t)2048 * 768 * 2;
    short* g    = (short*)p;  p += (size_t)2048 * 3072 * 2;
    short* Avqc = (short*)p;  p += (size_t)8192 * 768 * 2;
    short* partb = (short*)p; p += (size_t)4 * 2048 * 768 * 2;   // 12.6 MB split-K partials
    short* wreg = (short*)p;  p += (size_t)5900544 * 2;
    short* Wqkvb = wreg;
    short* Wob   = wreg + 1769472;
    short* fc1b  = wreg + 2359296;
    short* vqcb  = wreg + 2951424;
    short* fc2b  = wreg + 3541248;

    dim3 blk(256);
    const size_t SP = (size_t)2048 * 768;

    // 0. preamble: ln1 + bias concat + QKV weight conversion only (3777 blocks)
    preamble<<<3777, blk, 0, stream>>>(Wq, Wk, Wv, Wo, fc1_W, vqc_W, fc2_W, wreg,
                                       bq, bk, bv, bqkv, x, ln1_w, ln1_b, actb);
    // 1. fused QKV projection (576 GEMM blocks) + qn/kn side outputs
    //    + 1026 appended converter blocks (y >= 32, dispatched last)
    gemm_bf16<3, 64><<<dim3(18, 89, 1), blk, 0, stream>>>(actb, 768, Wqkvb, 768, bqkv,
                                                          Qb, 768, 0, Kfb, Vfb, 2304, 768, 0,
                                                          qnG, knG,
                                                          Wo, fc1_W, vqc_W, fc2_W, wreg);
    // 2. MFMA attention (swapped-QK + setprio + exp2-fold), 768 blocks (3/CU)
    attn_mfma<<<768, blk, 0, stream>>>(Qb, Kfb, Vfb, pond, qnG, knG, actb);
    // 3. Wo split-K x4 (768 blocks = 3/CU)
    gemm_bf16<5, 64><<<dim3(6, 32, 4), blk, 0, stream>>>(actb, 768, Wob, 768, nullptr,
                                                         partb, 768, SP,
                                                         nullptr, nullptr, 768, 192, 0,
                                                         nullptr, nullptr,
                                                         nullptr, nullptr, nullptr, nullptr, nullptr);
    // 4. reduce + bo + residual(x) -> x2 fp32, fused single-pass ln2 -> actb
    reduce_wo_ln<<<2048, blk, 0, stream>>>(partb, bo, x, ln2_w, ln2_b, x2, actb);
    // 5. fc1 split-K x4, cols 0..767 only (768 blocks = 3/CU exact)
    gemm_bf16<5, 64><<<dim3(6, 32, 4), blk, 0, stream>>>(actb, 768, fc1b, 768, nullptr,
                                                         partb, 768, SP,
                                                         nullptr, nullptr, 768, 192, 0,
                                                         nullptr, nullptr,
                                                         nullptr, nullptr, nullptr, nullptr, nullptr);
    // 6. reduce + bias + joint 3-dot cols 768..770 + expand -> Avqc [8192][768]
    reduce_fc1_expand<<<2048, blk, 0, stream>>>(partb, fc1_b, actb, fc1b + 768 * 768, Avqc);
    // 7. vqc (direct) + bias + gelu + transpose scatter (768 blocks = 3/CU)
    gemm_bf16<2, 64><<<dim3(6, 128, 1), blk, 0, stream>>>(Avqc, 768, vqcb, 768, vqc_b,
                                                          g, 3072, 0, nullptr, nullptr, 768, 768, 1,
                                                          nullptr, nullptr,
                                                          nullptr, nullptr, nullptr, nullptr, nullptr);
    // 8. fc2 split-K x4 (768 blocks = 3/CU)
    gemm_bf16<5, 64><<<dim3(6, 32, 4), blk, 0, stream>>>(g, 3072, fc2b, 3072, nullptr,
                                                         partb, 768, SP,
                                                         nullptr, nullptr, 768, 768, 0,
                                                         nullptr, nullptr,
                                                         nullptr, nullptr, nullptr, nullptr, nullptr);
    // 9. reduce + bias + residual(x2) -> out fp32
    reduce_fc2<<<1536, blk, 0, stream>>>(partb, fc2_b, x2, out);
}